// Round 12
// baseline (125.494 us; speedup 1.0000x reference)
//
#include <hip/hip_runtime.h>

typedef unsigned short u16;
typedef unsigned int u32;
typedef float f4 __attribute__((ext_vector_type(4)));
typedef short s8v __attribute__((ext_vector_type(8)));
typedef unsigned short u16x4 __attribute__((ext_vector_type(4)));

__device__ __forceinline__ u16 f2bf(float f) {
    u32 u = __float_as_uint(f);
    u32 r = (u + 0x7FFFu + ((u >> 16) & 1u)) >> 16;
    return (u16)r;
}

#define GLDS16(g, l)                                                                   \
    __builtin_amdgcn_global_load_lds((const __attribute__((address_space(1))) u32*)(g),\
                                     (__attribute__((address_space(3))) u32*)(l), 16, 0, 0)

// ---------------------------------------------------------------------------
// Fused prep: all fp32->bf16 converts + both conv-weight transposes.
// ---------------------------------------------------------------------------
__global__ __launch_bounds__(256) void prep_kernel(
    const float* __restrict__ x0, const float* __restrict__ x1,
    const float* __restrict__ qw, const float* __restrict__ kvw,
    const float* __restrict__ pw, const float* __restrict__ w0,
    const float* __restrict__ w1,
    u16* __restrict__ x0b, u16* __restrict__ x1b, u16* __restrict__ qwb,
    u16* __restrict__ kvwb, u16* __restrict__ pwb,
    u16* __restrict__ Wc0, u16* __restrict__ Wc1)
{
    for (int u = blockIdx.x * 256 + threadIdx.x; u < 3383296; u += gridDim.x * 256) {
        if (u < 2072576) {
            const float* src; u16* dst; int idx;
            if (u < 1605632)      { src = x0;  dst = x0b;  idx = u; }
            else if (u < 2007040) { src = x1;  dst = x1b;  idx = u - 1605632; }
            else if (u < 2023424) { src = qw;  dst = qwb;  idx = u - 2007040; }
            else if (u < 2056192) { src = kvw; dst = kvwb; idx = u - 2023424; }
            else                  { src = pw;  dst = pwb;  idx = u - 2056192; }
            f4 v = *(const f4*)(src + (size_t)idx * 4);
            u16x4 o;
            o[0] = f2bf(v[0]); o[1] = f2bf(v[1]); o[2] = f2bf(v[2]); o[3] = f2bf(v[3]);
            *(u16x4*)(dst + (size_t)idx * 4) = o;
        } else if (u < 3121152) {
            int e = (u - 2072576) * 4;
            int o = e >> 14, rem = e & 16383;
            int khw = rem >> 8, c = rem & 255;
            u16x4 ov;
            #pragma unroll
            for (int j = 0; j < 4; ++j)
                ov[j] = f2bf(w0[(size_t)o * 16384 + (size_t)(c + j) * 64 + khw]);
            *(u16x4*)(Wc0 + (size_t)e) = ov;
        } else {
            int e = (u - 3121152) * 4;
            int o = e >> 12, rem = e & 4095;
            int khw = rem >> 8, c = rem & 255;
            u16x4 ov;
            #pragma unroll
            for (int j = 0; j < 4; ++j)
                ov[j] = f2bf(w1[(size_t)o * 4096 + (size_t)(c + j) * 16 + khw]);
            *(u16x4*)(Wc1 + (size_t)e) = ov;
        }
    }
}

// ---------------------------------------------------------------------------
// Merged Q-projection + conv dispatch (z-switch on flat block id).
// bid < 496: Q-proj tile -> Yq bf16.
// bid >= 496: conv tile; split-K slice buffers (Ksl=1024, no atomics).
// Single-buffer staging (round-10 proven; dbuf regressed: occupancy loss,
// barrier still drains vmcnt(0) so no overlap gained).
// ---------------------------------------------------------------------------
__global__ __launch_bounds__(256) void qc_kernel(
    const u16* __restrict__ x0b, const u16* __restrict__ x1b,
    const u16* __restrict__ qwb, u16* __restrict__ Yq,
    const u16* __restrict__ Wc0, const u16* __restrict__ Wc1,
    float* __restrict__ xr0, float* __restrict__ xr1)
{
    __shared__ u16 lsA[128 * 64];
    __shared__ u16 lsB[128 * 64];
    int bid = blockIdx.x;
    int tid = threadIdx.x;
    int w = tid >> 6, l = tid & 63, g = l >> 4, lq = l & 15;
    int wr = w >> 1, wc = w & 1;

    f4 acc[4][4];
    #pragma unroll
    for (int i = 0; i < 4; ++i)
        #pragma unroll
        for (int j = 0; j < 4; ++j) acc[i][j] = (f4){0.f, 0.f, 0.f, 0.f};

    if (bid < 496) {
        int x = bid & 1, y = (bid >> 1) % 31, bz = bid / 62;
        int m0 = y * 128, n0 = x * 128;
        const u16* aptr[4];
        long boff[4];
        #pragma unroll
        for (int i = 0; i < 4; ++i) {
            int p = (w * 4 + i) * 64 + l;
            int r = p >> 3, cp = p & 7;
            int ar = m0 + r; ar = ar < 3920 ? ar : 3919;
            const u16* base = (ar < 3136)
                ? x0b + ((size_t)bz * 3136 + ar) * 256
                : x1b + ((size_t)bz * 784 + (ar - 3136)) * 256;
            aptr[i] = base + ((cp ^ (r & 7)) << 3);
            boff[i] = (long)(n0 + r) * 256 + ((cp ^ (r & 7)) << 3);
        }
        for (int k0 = 0; k0 < 256; k0 += 64) {
            __syncthreads();
            #pragma unroll
            for (int i = 0; i < 4; ++i)
                GLDS16(aptr[i] + k0, &lsA[(w * 4 + i) * 512]);
            #pragma unroll
            for (int i = 0; i < 4; ++i)
                GLDS16(qwb + boff[i] + k0, &lsB[(w * 4 + i) * 512]);
            __syncthreads();
            #pragma unroll
            for (int kk = 0; kk < 2; ++kk) {
                s8v af[4], bf[4];
                #pragma unroll
                for (int mf = 0; mf < 4; ++mf) {
                    int row = wr * 64 + mf * 16 + lq;
                    int ph = (kk * 4 + g) ^ (row & 7);
                    af[mf] = *(const s8v*)&lsA[row * 64 + ph * 8];
                }
                #pragma unroll
                for (int nf = 0; nf < 4; ++nf) {
                    int row = wc * 64 + nf * 16 + lq;
                    int ph = (kk * 4 + g) ^ (row & 7);
                    bf[nf] = *(const s8v*)&lsB[row * 64 + ph * 8];
                }
                #pragma unroll
                for (int mf = 0; mf < 4; ++mf)
                    #pragma unroll
                    for (int nf = 0; nf < 4; ++nf)
                        acc[mf][nf] = __builtin_amdgcn_mfma_f32_16x16x32_bf16(
                            af[mf], bf[nf], acc[mf][nf], 0, 0, 0);
            }
        }
        #pragma unroll
        for (int mf = 0; mf < 4; ++mf)
            #pragma unroll
            for (int r = 0; r < 4; ++r) {
                int grow = m0 + wr * 64 + mf * 16 + g * 4 + r;
                if (grow < 3920) {
                    #pragma unroll
                    for (int nf = 0; nf < 4; ++nf) {
                        int col = n0 + wc * 64 + nf * 16 + lq;
                        Yq[((size_t)bz * 3920 + grow) * 256 + col] = f2bf(acc[mf][nf][r]);
                    }
                }
            }
    } else {
        int cb = bid - 496;
        int bx = cb & 1, by = (cb >> 1) & 3, z = cb >> 3;
        const u16* Xb; const u16* Wcp; float* Co;
        int Npix, Wimg, lgs, Kc, zz;
        if (z < 16) { Xb = x0b; Wcp = Wc0; Co = xr0; Npix = 3136; Wimg = 56; lgs = 3; Kc = 16384; zz = z; }
        else        { Xb = x1b; Wcp = Wc1; Co = xr1; Npix = 784;  Wimg = 28; lgs = 2; Kc = 4096;  zz = z - 16; }
        int s = 1 << lgs;
        int m0 = by * 128, n0 = bx * 128;

        long aoff[4], boff[4];
        #pragma unroll
        for (int i = 0; i < 4; ++i) {
            int p = (w * 4 + i) * 64 + l;
            int r = p >> 3, cp = p & 7;
            int rr = m0 + r; rr = rr < 392 ? rr : 391;
            int bb = rr / 49, pp = rr % 49;
            int ph = pp / 7, pw = pp % 7;
            aoff[i] = ((long)bb * Npix + (long)(ph * Wimg + pw) * s) * 256 + ((cp ^ (r & 7)) << 3);
            boff[i] = (long)(n0 + r) * Kc + ((cp ^ (r & 7)) << 3);
        }
        int kbase = zz * 1024;
        for (int ko = 0; ko < 1024; ko += 64) {
            int k0 = kbase + ko;
            int khw = k0 >> 8;
            int kh = khw >> lgs, kw = khw & (s - 1);
            long adelta = (long)(kh * Wimg + kw) * 256 + (k0 & 255);
            __syncthreads();
            #pragma unroll
            for (int i = 0; i < 4; ++i)
                GLDS16(Xb + aoff[i] + adelta, &lsA[(w * 4 + i) * 512]);
            #pragma unroll
            for (int i = 0; i < 4; ++i)
                GLDS16(Wcp + boff[i] + k0, &lsB[(w * 4 + i) * 512]);
            __syncthreads();
            #pragma unroll
            for (int kk = 0; kk < 2; ++kk) {
                s8v af[4], bf[4];
                #pragma unroll
                for (int mf = 0; mf < 4; ++mf) {
                    int row = wr * 64 + mf * 16 + lq;
                    int ph2 = (kk * 4 + g) ^ (row & 7);
                    af[mf] = *(const s8v*)&lsA[row * 64 + ph2 * 8];
                }
                #pragma unroll
                for (int nf = 0; nf < 4; ++nf) {
                    int row = wc * 64 + nf * 16 + lq;
                    int ph2 = (kk * 4 + g) ^ (row & 7);
                    bf[nf] = *(const s8v*)&lsB[row * 64 + ph2 * 8];
                }
                #pragma unroll
                for (int mf = 0; mf < 4; ++mf)
                    #pragma unroll
                    for (int nf = 0; nf < 4; ++nf)
                        acc[mf][nf] = __builtin_amdgcn_mfma_f32_16x16x32_bf16(
                            af[mf], bf[nf], acc[mf][nf], 0, 0, 0);
            }
        }
        float* Cb = Co + (size_t)zz * 392 * 256;
        #pragma unroll
        for (int mf = 0; mf < 4; ++mf)
            #pragma unroll
            for (int r = 0; r < 4; ++r) {
                int grow = m0 + wr * 64 + mf * 16 + g * 4 + r;
                if (grow < 392) {
                    #pragma unroll
                    for (int nf = 0; nf < 4; ++nf) {
                        int col = n0 + wc * 64 + nf * 16 + lq;
                        Cb[(size_t)grow * 256 + col] = acc[mf][nf][r];
                    }
                }
            }
    }
}

// ---------------------------------------------------------------------------
// LayerNorm: sum conv slices (16 / 4) + conv bias, normalize, write bf16.
// ---------------------------------------------------------------------------
__global__ __launch_bounds__(256) void ln_kernel(
    const float* __restrict__ xr0, const float* __restrict__ xr1,
    const float* __restrict__ srb0, const float* __restrict__ srb1,
    const float* __restrict__ n0w, const float* __restrict__ n0b,
    const float* __restrict__ n1w, const float* __restrict__ n1b,
    u16* __restrict__ lnb)
{
    int row = blockIdx.x;            // 0..783
    int b = row / 98, j = row % 98;
    int c = threadIdx.x;
    const float* src; int sidx, ns;
    const float *bs, *nw, *nb;
    if (j < 49) { src = xr0; sidx = b * 49 + j;       ns = 16; bs = srb0; nw = n0w; nb = n0b; }
    else        { src = xr1; sidx = b * 49 + (j - 49); ns = 4; bs = srb1; nw = n1w; nb = n1b; }
    float v = bs[c];
    for (int sl = 0; sl < ns; ++sl) v += src[(size_t)sl * 100352 + (size_t)sidx * 256 + c];
    __shared__ float red[8];
    float sumv = v;
    #pragma unroll
    for (int off = 32; off; off >>= 1) sumv += __shfl_down(sumv, off, 64);
    int wid = c >> 6, lane = c & 63;
    if (lane == 0) red[wid] = sumv;
    __syncthreads();
    float mu = (red[0] + red[1] + red[2] + red[3]) * (1.0f / 256.0f);
    float dv = v - mu;
    float s2 = dv * dv;
    #pragma unroll
    for (int off = 32; off; off >>= 1) s2 += __shfl_down(s2, off, 64);
    if (lane == 0) red[4 + wid] = s2;
    __syncthreads();
    float var = (red[4] + red[5] + red[6] + red[7]) * (1.0f / 256.0f);
    float rr = rsqrtf(var + 1e-5f);
    lnb[(size_t)row * 256 + c] = f2bf(dv * rr * nw[c] + nb[c]);
}

// ---------------------------------------------------------------------------
// KV projection -> Kb[bh][112][32] (rows>=98 zero), Vtb[bh][32][128]
// (cols>=98 zero). Grid (4, 1, 8). Single-buffer staging (round-10 proven).
// ---------------------------------------------------------------------------
__global__ __launch_bounds__(256) void kv_kernel(
    const u16* __restrict__ A, const u16* __restrict__ Bw,
    u16* __restrict__ Kb, u16* __restrict__ Vtb)
{
    __shared__ u16 lsA[128 * 64];
    __shared__ u16 lsB[128 * 64];
    int tid = threadIdx.x;
    int w = tid >> 6, l = tid & 63, g = l >> 4, lq = l & 15;
    int wr = w >> 1, wc = w & 1;
    int n0 = blockIdx.x * 128;
    int bz = blockIdx.z;
    const u16* Ab = A + (size_t)bz * 98 * 256;

    long aoff[4], boff[4];
    #pragma unroll
    for (int i = 0; i < 4; ++i) {
        int p = (w * 4 + i) * 64 + l;
        int r = p >> 3, cp = p & 7;
        int ar = r < 98 ? r : 97;
        aoff[i] = (long)ar * 256 + ((cp ^ (r & 7)) << 3);
        boff[i] = (long)(n0 + r) * 256 + ((cp ^ (r & 7)) << 3);
    }
    f4 acc[4][4];
    #pragma unroll
    for (int i = 0; i < 4; ++i)
        #pragma unroll
        for (int j = 0; j < 4; ++j) acc[i][j] = (f4){0.f, 0.f, 0.f, 0.f};

    for (int k0 = 0; k0 < 256; k0 += 64) {
        __syncthreads();
        #pragma unroll
        for (int i = 0; i < 4; ++i)
            GLDS16(Ab + aoff[i] + k0, &lsA[(w * 4 + i) * 512]);
        #pragma unroll
        for (int i = 0; i < 4; ++i)
            GLDS16(Bw + boff[i] + k0, &lsB[(w * 4 + i) * 512]);
        __syncthreads();
        #pragma unroll
        for (int kk = 0; kk < 2; ++kk) {
            s8v af[4], bf[4];
            #pragma unroll
            for (int mf = 0; mf < 4; ++mf) {
                int row = wr * 64 + mf * 16 + lq;
                int ph = (kk * 4 + g) ^ (row & 7);
                af[mf] = *(const s8v*)&lsA[row * 64 + ph * 8];
            }
            #pragma unroll
            for (int nf = 0; nf < 4; ++nf) {
                int row = wc * 64 + nf * 16 + lq;
                int ph = (kk * 4 + g) ^ (row & 7);
                bf[nf] = *(const s8v*)&lsB[row * 64 + ph * 8];
            }
            #pragma unroll
            for (int mf = 0; mf < 4; ++mf)
                #pragma unroll
                for (int nf = 0; nf < 4; ++nf)
                    acc[mf][nf] = __builtin_amdgcn_mfma_f32_16x16x32_bf16(
                        af[mf], bf[nf], acc[mf][nf], 0, 0, 0);
        }
    }
    #pragma unroll
    for (int mf = 0; mf < 4; ++mf)
        #pragma unroll
        for (int r = 0; r < 4; ++r) {
            int grow = wr * 64 + mf * 16 + g * 4 + r;   // 0..127
            #pragma unroll
            for (int nf = 0; nf < 4; ++nf) {
                int col = n0 + wc * 64 + nf * 16 + lq;
                u16 bv = (grow < 98) ? f2bf(acc[mf][nf][r]) : (u16)0;
                if (col < 256) {
                    if (grow < 112)
                        Kb[((size_t)(bz * 8 + (col >> 5)) * 112 + grow) * 32 + (col & 31)] = bv;
                } else {
                    int cc = col - 256;
                    Vtb[((size_t)(bz * 8 + (cc >> 5)) * 32 + (cc & 31)) * 128 + grow] = bv;
                }
            }
        }
}

// ---------------------------------------------------------------------------
// Fused attention + output projection. Grid (123, 8), 512 threads (8 waves).
// Q-tile = 32 rows (was 64): 984 blocks, LDS 48 KB -> 3 blocks/CU, ~24
// waves/CU resident (was ~15) for latency hiding. Per-query math identical.
// ---------------------------------------------------------------------------
#define SCALE_F 0.1767766952966369f
__global__ __launch_bounds__(512) void attnout_kernel(
    const u16* __restrict__ Yq, const u16* __restrict__ Kb,
    const u16* __restrict__ Vtb, const u16* __restrict__ pwb,
    const float* __restrict__ proj_b, float* __restrict__ out)
{
    __shared__ u16 Ps[8][16 * 128];    // per-wave P scratch (4 KB each)
    __shared__ u16 Os[32 * 256];       // O panel, swizzled (16 KB)
    int tid = threadIdx.x;
    int w = tid >> 6, l = tid & 63, g = l >> 4, lq = l & 15;
    int b = blockIdx.y, h = w;
    int n0 = blockIdx.x * 32;
    const u16* Kh = Kb + (size_t)(b * 8 + h) * 112 * 32;
    const u16* Vh = Vtb + (size_t)(b * 8 + h) * 32 * 128;
    u16* Pw = Ps[w];

    // zero P pad granules 14,15 (keys 112..127) once
    if (l < 32) {
        int row = l >> 1;
        int gr = (14 + (l & 1)) ^ (row & 7);
        *(s8v*)&Pw[row * 128 + gr * 8] = (s8v){0, 0, 0, 0, 0, 0, 0, 0};
    }

    for (int qt = 0; qt < 2; ++qt) {
        int qrow = n0 + qt * 16 + lq;
        int qr = qrow < 3920 ? qrow : 3919;
        s8v qf = *(const s8v*)(Yq + ((size_t)b * 3920 + qr) * 256 + h * 32 + g * 8);
        f4 sacc[7];
        #pragma unroll
        for (int f = 0; f < 7; ++f) {
            s8v kf = *(const s8v*)(Kh + (f * 16 + lq) * 32 + g * 8);
            f4 zz = (f4){0.f, 0.f, 0.f, 0.f};
            sacc[f] = __builtin_amdgcn_mfma_f32_16x16x32_bf16(kf, qf, zz, 0, 0, 0);
        }
        float pm = -1e30f;
        float sv[7][4];
        #pragma unroll
        for (int f = 0; f < 7; ++f)
            #pragma unroll
            for (int r = 0; r < 4; ++r) {
                int key = f * 16 + g * 4 + r;
                float v = sacc[f][r] * SCALE_F;
                if (key >= 98) v = -1e30f;
                sv[f][r] = v;
                pm = fmaxf(pm, v);
            }
        pm = fmaxf(pm, __shfl_xor(pm, 16));
        pm = fmaxf(pm, __shfl_xor(pm, 32));
        float sum = 0.f;
        float pv[7][4];
        #pragma unroll
        for (int f = 0; f < 7; ++f)
            #pragma unroll
            for (int r = 0; r < 4; ++r) {
                float e = __expf(sv[f][r] - pm);
                pv[f][r] = e;
                sum += e;
            }
        sum += __shfl_xor(sum, 16);
        sum += __shfl_xor(sum, 32);
        float inv = 1.0f / sum;

        #pragma unroll
        for (int f = 0; f < 7; ++f)
            #pragma unroll
            for (int pr = 0; pr < 2; ++pr) {
                u32 pk = (u32)f2bf(pv[f][2 * pr] * inv) |
                         ((u32)f2bf(pv[f][2 * pr + 1] * inv) << 16);
                int k = f * 16 + g * 4 + pr * 2;
                int gr = (k >> 3) ^ (lq & 7);
                *(u32*)&Pw[lq * 128 + gr * 8 + (k & 7)] = pk;
            }

        f4 o0 = (f4){0.f, 0.f, 0.f, 0.f}, o1 = (f4){0.f, 0.f, 0.f, 0.f};
        #pragma unroll
        for (int s4 = 0; s4 < 4; ++s4) {
            int gv = s4 * 4 + g;
            s8v pa = *(const s8v*)&Pw[lq * 128 + ((gv ^ (lq & 7)) * 8)];
            s8v vf0 = *(const s8v*)(Vh + (size_t)lq * 128 + s4 * 32 + g * 8);
            s8v vf1 = *(const s8v*)(Vh + (size_t)(16 + lq) * 128 + s4 * 32 + g * 8);
            o0 = __builtin_amdgcn_mfma_f32_16x16x32_bf16(pa, vf0, o0, 0, 0, 0);
            o1 = __builtin_amdgcn_mfma_f32_16x16x32_bf16(pa, vf1, o1, 0, 0, 0);
        }
        #pragma unroll
        for (int r = 0; r < 4; ++r) {
            int R = qt * 16 + g * 4 + r;
            #pragma unroll
            for (int half = 0; half < 2; ++half) {
                int C = h * 32 + half * 16 + lq;
                int sg = (C >> 3) ^ (R & 7);
                Os[R * 256 + sg * 8 + (C & 7)] = f2bf(half ? o1[r] : o0[r]);
            }
        }
    }
    __syncthreads();

    // ---- out-proj: C[32 x 256] = O[32 x 256] * pwb^T + bias ----
    f4 acc[2][2];
    #pragma unroll
    for (int i = 0; i < 2; ++i) {
        acc[i][0] = (f4){0.f, 0.f, 0.f, 0.f};
        acc[i][1] = (f4){0.f, 0.f, 0.f, 0.f};
    }
    for (int k0 = 0; k0 < 256; k0 += 32) {
        s8v af[2], bf[2];
        int kgr = (k0 >> 3) + g;
        #pragma unroll
        for (int mf = 0; mf < 2; ++mf) {
            int row = mf * 16 + lq;
            af[mf] = *(const s8v*)&Os[row * 256 + ((kgr ^ (row & 7)) * 8)];
        }
        #pragma unroll
        for (int nf = 0; nf < 2; ++nf) {
            int n = w * 32 + nf * 16 + lq;
            bf[nf] = *(const s8v*)(pwb + (size_t)n * 256 + k0 + g * 8);
        }
        #pragma unroll
        for (int mf = 0; mf < 2; ++mf)
            #pragma unroll
            for (int nf = 0; nf < 2; ++nf)
                acc[mf][nf] = __builtin_amdgcn_mfma_f32_16x16x32_bf16(
                    af[mf], bf[nf], acc[mf][nf], 0, 0, 0);
    }
    #pragma unroll
    for (int mf = 0; mf < 2; ++mf)
        #pragma unroll
        for (int r = 0; r < 4; ++r) {
            int grow = n0 + mf * 16 + g * 4 + r;
            if (grow < 3920) {
                #pragma unroll
                for (int nf = 0; nf < 2; ++nf) {
                    int col = w * 32 + nf * 16 + lq;
                    out[((size_t)b * 3920 + grow) * 256 + col] = acc[mf][nf][r] + proj_b[col];
                }
            }
        }
}

// ---------------------------------------------------------------------------
extern "C" void kernel_launch(void* const* d_in, const int* in_sizes, int n_in,
                              void* d_out, int out_size, void* d_ws, size_t ws_size,
                              hipStream_t stream)
{
    const float* x0     = (const float*)d_in[0];
    const float* x1     = (const float*)d_in[1];
    const float* q_w    = (const float*)d_in[2];
    const float* kv_w   = (const float*)d_in[3];
    const float* proj_w = (const float*)d_in[4];
    const float* proj_b = (const float*)d_in[5];
    const float* sr0_w  = (const float*)d_in[6];
    const float* sr0_b  = (const float*)d_in[7];
    const float* sr1_w  = (const float*)d_in[8];
    const float* sr1_b  = (const float*)d_in[9];
    const float* n0w    = (const float*)d_in[10];
    const float* n0b    = (const float*)d_in[11];
    const float* n1w    = (const float*)d_in[12];
    const float* n1b    = (const float*)d_in[13];
    (void)in_sizes; (void)n_in; (void)out_size; (void)ws_size;

    float* ws = (float*)d_ws;
    u16*  Yq   = (u16*)ws;                         // [8][3920][256] bf16
    u16*  x0b  = (u16*)(ws + 4014080);             // [25088][256] bf16
    u16*  x1b  = (u16*)(ws + 7225344);             // [6272][256] bf16
    float* xr0 = ws + 8028160;                     // [16][392][256] fp32 slices
    float* xr1 = ws + 9633792;                     // [4][392][256]
    u16*  Kb   = (u16*)(ws + 10035200);            // [64][112][32] bf16
    u16*  Vtb  = (u16*)(ws + 10149888);            // [64][32][128] bf16
    u16*  qwb  = (u16*)(ws + 10280960);            // [256][256] bf16
    u16*  kvwb = (u16*)(ws + 10313728);            // [512][256] bf16
    u16*  pwb  = (u16*)(ws + 10379264);            // [256][256] bf16
    u16*  Wc0  = (u16*)(ws + 10412032);            // [256][16384] bf16
    u16*  Wc1  = (u16*)(ws + 12509184);            // [256][4096] bf16
    u16*  lnb  = (u16*)(ws + 13033472);            // [784][256] bf16

    // 1. fused converts + weight transposes
    prep_kernel<<<2048, 256, 0, stream>>>(
        x0, x1, q_w, kv_w, proj_w, sr0_w, sr1_w,
        x0b, x1b, qwb, kvwb, pwb, Wc0, Wc1);

    // 2. Q projection + convs (single-buffer staging), one dispatch
    qc_kernel<<<656, 256, 0, stream>>>(x0b, x1b, qwb, Yq, Wc0, Wc1, xr0, xr1);

    // 3. layernorm (+conv bias, slice reduce) -> bf16, 784 blocks
    ln_kernel<<<784, 256, 0, stream>>>(xr0, xr1, sr0_b, sr1_b, n0w, n0b, n1w, n1b, lnb);

    // 4. KV projection -> Kb/Vtb (attnout layouts)
    kv_kernel<<<dim3(4, 1, 8), 256, 0, stream>>>(lnb, kvwb, Kb, Vtb);

    // 5. fused attention + output projection -> d_out fp32 (32-row Q-tiles)
    attnout_kernel<<<dim3(123, 8), 512, 0, stream>>>(
        Yq, Kb, Vtb, pwb, proj_b, (float*)d_out);
}

// Round 13
// 106.726 us; speedup vs baseline: 1.1759x; 1.1759x over previous
//
#include <hip/hip_runtime.h>

typedef unsigned short u16;
typedef unsigned int u32;
typedef float f4 __attribute__((ext_vector_type(4)));
typedef short s8v __attribute__((ext_vector_type(8)));
typedef unsigned short u16x4 __attribute__((ext_vector_type(4)));

__device__ __forceinline__ u16 f2bf(float f) {
    u32 u = __float_as_uint(f);
    u32 r = (u + 0x7FFFu + ((u >> 16) & 1u)) >> 16;
    return (u16)r;
}

#define GLDS16(g, l)                                                                   \
    __builtin_amdgcn_global_load_lds((const __attribute__((address_space(1))) u32*)(g),\
                                     (__attribute__((address_space(3))) u32*)(l), 16, 0, 0)

// ---------------------------------------------------------------------------
// Fused prep: all fp32->bf16 converts + both conv-weight transposes.
// ---------------------------------------------------------------------------
__global__ __launch_bounds__(256) void prep_kernel(
    const float* __restrict__ x0, const float* __restrict__ x1,
    const float* __restrict__ qw, const float* __restrict__ kvw,
    const float* __restrict__ pw, const float* __restrict__ w0,
    const float* __restrict__ w1,
    u16* __restrict__ x0b, u16* __restrict__ x1b, u16* __restrict__ qwb,
    u16* __restrict__ kvwb, u16* __restrict__ pwb,
    u16* __restrict__ Wc0, u16* __restrict__ Wc1)
{
    for (int u = blockIdx.x * 256 + threadIdx.x; u < 3383296; u += gridDim.x * 256) {
        if (u < 2072576) {
            const float* src; u16* dst; int idx;
            if (u < 1605632)      { src = x0;  dst = x0b;  idx = u; }
            else if (u < 2007040) { src = x1;  dst = x1b;  idx = u - 1605632; }
            else if (u < 2023424) { src = qw;  dst = qwb;  idx = u - 2007040; }
            else if (u < 2056192) { src = kvw; dst = kvwb; idx = u - 2023424; }
            else                  { src = pw;  dst = pwb;  idx = u - 2056192; }
            f4 v = *(const f4*)(src + (size_t)idx * 4);
            u16x4 o;
            o[0] = f2bf(v[0]); o[1] = f2bf(v[1]); o[2] = f2bf(v[2]); o[3] = f2bf(v[3]);
            *(u16x4*)(dst + (size_t)idx * 4) = o;
        } else if (u < 3121152) {
            int e = (u - 2072576) * 4;
            int o = e >> 14, rem = e & 16383;
            int khw = rem >> 8, c = rem & 255;
            u16x4 ov;
            #pragma unroll
            for (int j = 0; j < 4; ++j)
                ov[j] = f2bf(w0[(size_t)o * 16384 + (size_t)(c + j) * 64 + khw]);
            *(u16x4*)(Wc0 + (size_t)e) = ov;
        } else {
            int e = (u - 3121152) * 4;
            int o = e >> 12, rem = e & 4095;
            int khw = rem >> 8, c = rem & 255;
            u16x4 ov;
            #pragma unroll
            for (int j = 0; j < 4; ++j)
                ov[j] = f2bf(w1[(size_t)o * 4096 + (size_t)(c + j) * 16 + khw]);
            *(u16x4*)(Wc1 + (size_t)e) = ov;
        }
    }
}

// ---------------------------------------------------------------------------
// Merged conv + Q-projection dispatch, LPT-ordered: conv tiles (4x longer,
// K=1024) are bid 0..159 so they start at t=0; qproj tiles (K=256) backfill.
// conv: split-K slice buffers (Ksl=1024, no atomics).
// ---------------------------------------------------------------------------
__global__ __launch_bounds__(256) void qc_kernel(
    const u16* __restrict__ x0b, const u16* __restrict__ x1b,
    const u16* __restrict__ qwb, u16* __restrict__ Yq,
    const u16* __restrict__ Wc0, const u16* __restrict__ Wc1,
    float* __restrict__ xr0, float* __restrict__ xr1)
{
    __shared__ u16 lsA[128 * 64];
    __shared__ u16 lsB[128 * 64];
    int bid = blockIdx.x;
    int tid = threadIdx.x;
    int w = tid >> 6, l = tid & 63, g = l >> 4, lq = l & 15;
    int wr = w >> 1, wc = w & 1;

    f4 acc[4][4];
    #pragma unroll
    for (int i = 0; i < 4; ++i)
        #pragma unroll
        for (int j = 0; j < 4; ++j) acc[i][j] = (f4){0.f, 0.f, 0.f, 0.f};

    if (bid >= 160) {
        // ------------------- Q projection (short blocks, backfill) ---------
        int bid2 = bid - 160;
        int x = bid2 & 1, y = (bid2 >> 1) % 31, bz = bid2 / 62;
        int m0 = y * 128, n0 = x * 128;
        const u16* aptr[4];
        long boff[4];
        #pragma unroll
        for (int i = 0; i < 4; ++i) {
            int p = (w * 4 + i) * 64 + l;
            int r = p >> 3, cp = p & 7;
            int ar = m0 + r; ar = ar < 3920 ? ar : 3919;
            const u16* base = (ar < 3136)
                ? x0b + ((size_t)bz * 3136 + ar) * 256
                : x1b + ((size_t)bz * 784 + (ar - 3136)) * 256;
            aptr[i] = base + ((cp ^ (r & 7)) << 3);
            boff[i] = (long)(n0 + r) * 256 + ((cp ^ (r & 7)) << 3);
        }
        for (int k0 = 0; k0 < 256; k0 += 64) {
            __syncthreads();
            #pragma unroll
            for (int i = 0; i < 4; ++i)
                GLDS16(aptr[i] + k0, &lsA[(w * 4 + i) * 512]);
            #pragma unroll
            for (int i = 0; i < 4; ++i)
                GLDS16(qwb + boff[i] + k0, &lsB[(w * 4 + i) * 512]);
            __syncthreads();
            #pragma unroll
            for (int kk = 0; kk < 2; ++kk) {
                s8v af[4], bf[4];
                #pragma unroll
                for (int mf = 0; mf < 4; ++mf) {
                    int row = wr * 64 + mf * 16 + lq;
                    int ph = (kk * 4 + g) ^ (row & 7);
                    af[mf] = *(const s8v*)&lsA[row * 64 + ph * 8];
                }
                #pragma unroll
                for (int nf = 0; nf < 4; ++nf) {
                    int row = wc * 64 + nf * 16 + lq;
                    int ph = (kk * 4 + g) ^ (row & 7);
                    bf[nf] = *(const s8v*)&lsB[row * 64 + ph * 8];
                }
                #pragma unroll
                for (int mf = 0; mf < 4; ++mf)
                    #pragma unroll
                    for (int nf = 0; nf < 4; ++nf)
                        acc[mf][nf] = __builtin_amdgcn_mfma_f32_16x16x32_bf16(
                            af[mf], bf[nf], acc[mf][nf], 0, 0, 0);
            }
        }
        #pragma unroll
        for (int mf = 0; mf < 4; ++mf)
            #pragma unroll
            for (int r = 0; r < 4; ++r) {
                int grow = m0 + wr * 64 + mf * 16 + g * 4 + r;
                if (grow < 3920) {
                    #pragma unroll
                    for (int nf = 0; nf < 4; ++nf) {
                        int col = n0 + wc * 64 + nf * 16 + lq;
                        Yq[((size_t)bz * 3920 + grow) * 256 + col] = f2bf(acc[mf][nf][r]);
                    }
                }
            }
    } else {
        // ------------------- conv (long blocks, start first) ---------------
        int cb = bid;
        int bx = cb & 1, by = (cb >> 1) & 3, z = cb >> 3;
        const u16* Xb; const u16* Wcp; float* Co;
        int Npix, Wimg, lgs, Kc, zz;
        if (z < 16) { Xb = x0b; Wcp = Wc0; Co = xr0; Npix = 3136; Wimg = 56; lgs = 3; Kc = 16384; zz = z; }
        else        { Xb = x1b; Wcp = Wc1; Co = xr1; Npix = 784;  Wimg = 28; lgs = 2; Kc = 4096;  zz = z - 16; }
        int s = 1 << lgs;
        int m0 = by * 128, n0 = bx * 128;

        long aoff[4], boff[4];
        #pragma unroll
        for (int i = 0; i < 4; ++i) {
            int p = (w * 4 + i) * 64 + l;
            int r = p >> 3, cp = p & 7;
            int rr = m0 + r; rr = rr < 392 ? rr : 391;
            int bb = rr / 49, pp = rr % 49;
            int ph = pp / 7, pw = pp % 7;
            aoff[i] = ((long)bb * Npix + (long)(ph * Wimg + pw) * s) * 256 + ((cp ^ (r & 7)) << 3);
            boff[i] = (long)(n0 + r) * Kc + ((cp ^ (r & 7)) << 3);
        }
        int kbase = zz * 1024;
        for (int ko = 0; ko < 1024; ko += 64) {
            int k0 = kbase + ko;
            int khw = k0 >> 8;
            int kh = khw >> lgs, kw = khw & (s - 1);
            long adelta = (long)(kh * Wimg + kw) * 256 + (k0 & 255);
            __syncthreads();
            #pragma unroll
            for (int i = 0; i < 4; ++i)
                GLDS16(Xb + aoff[i] + adelta, &lsA[(w * 4 + i) * 512]);
            #pragma unroll
            for (int i = 0; i < 4; ++i)
                GLDS16(Wcp + boff[i] + k0, &lsB[(w * 4 + i) * 512]);
            __syncthreads();
            #pragma unroll
            for (int kk = 0; kk < 2; ++kk) {
                s8v af[4], bf[4];
                #pragma unroll
                for (int mf = 0; mf < 4; ++mf) {
                    int row = wr * 64 + mf * 16 + lq;
                    int ph2 = (kk * 4 + g) ^ (row & 7);
                    af[mf] = *(const s8v*)&lsA[row * 64 + ph2 * 8];
                }
                #pragma unroll
                for (int nf = 0; nf < 4; ++nf) {
                    int row = wc * 64 + nf * 16 + lq;
                    int ph2 = (kk * 4 + g) ^ (row & 7);
                    bf[nf] = *(const s8v*)&lsB[row * 64 + ph2 * 8];
                }
                #pragma unroll
                for (int mf = 0; mf < 4; ++mf)
                    #pragma unroll
                    for (int nf = 0; nf < 4; ++nf)
                        acc[mf][nf] = __builtin_amdgcn_mfma_f32_16x16x32_bf16(
                            af[mf], bf[nf], acc[mf][nf], 0, 0, 0);
            }
        }
        float* Cb = Co + (size_t)zz * 392 * 256;
        #pragma unroll
        for (int mf = 0; mf < 4; ++mf)
            #pragma unroll
            for (int r = 0; r < 4; ++r) {
                int grow = m0 + wr * 64 + mf * 16 + g * 4 + r;
                if (grow < 392) {
                    #pragma unroll
                    for (int nf = 0; nf < 4; ++nf) {
                        int col = n0 + wc * 64 + nf * 16 + lq;
                        Cb[(size_t)grow * 256 + col] = acc[mf][nf][r];
                    }
                }
            }
    }
}

// ---------------------------------------------------------------------------
// LayerNorm: sum conv slices (16 / 4) + conv bias, normalize, write bf16.
// ---------------------------------------------------------------------------
__global__ __launch_bounds__(256) void ln_kernel(
    const float* __restrict__ xr0, const float* __restrict__ xr1,
    const float* __restrict__ srb0, const float* __restrict__ srb1,
    const float* __restrict__ n0w, const float* __restrict__ n0b,
    const float* __restrict__ n1w, const float* __restrict__ n1b,
    u16* __restrict__ lnb)
{
    int row = blockIdx.x;            // 0..783
    int b = row / 98, j = row % 98;
    int c = threadIdx.x;
    const float* src; int sidx, ns;
    const float *bs, *nw, *nb;
    if (j < 49) { src = xr0; sidx = b * 49 + j;       ns = 16; bs = srb0; nw = n0w; nb = n0b; }
    else        { src = xr1; sidx = b * 49 + (j - 49); ns = 4; bs = srb1; nw = n1w; nb = n1b; }
    float v = bs[c];
    for (int sl = 0; sl < ns; ++sl) v += src[(size_t)sl * 100352 + (size_t)sidx * 256 + c];
    __shared__ float red[8];
    float sumv = v;
    #pragma unroll
    for (int off = 32; off; off >>= 1) sumv += __shfl_down(sumv, off, 64);
    int wid = c >> 6, lane = c & 63;
    if (lane == 0) red[wid] = sumv;
    __syncthreads();
    float mu = (red[0] + red[1] + red[2] + red[3]) * (1.0f / 256.0f);
    float dv = v - mu;
    float s2 = dv * dv;
    #pragma unroll
    for (int off = 32; off; off >>= 1) s2 += __shfl_down(s2, off, 64);
    if (lane == 0) red[4 + wid] = s2;
    __syncthreads();
    float var = (red[4] + red[5] + red[6] + red[7]) * (1.0f / 256.0f);
    float rr = rsqrtf(var + 1e-5f);
    lnb[(size_t)row * 256 + c] = f2bf(dv * rr * nw[c] + nb[c]);
}

// ---------------------------------------------------------------------------
// KV projection -> Kb[bh][112][32] (rows>=98 zero), Vtb[bh][32][128]
// (cols>=98 zero). Grid (4, 1, 8).
// ---------------------------------------------------------------------------
__global__ __launch_bounds__(256) void kv_kernel(
    const u16* __restrict__ A, const u16* __restrict__ Bw,
    u16* __restrict__ Kb, u16* __restrict__ Vtb)
{
    __shared__ u16 lsA[128 * 64];
    __shared__ u16 lsB[128 * 64];
    int tid = threadIdx.x;
    int w = tid >> 6, l = tid & 63, g = l >> 4, lq = l & 15;
    int wr = w >> 1, wc = w & 1;
    int n0 = blockIdx.x * 128;
    int bz = blockIdx.z;
    const u16* Ab = A + (size_t)bz * 98 * 256;

    long aoff[4], boff[4];
    #pragma unroll
    for (int i = 0; i < 4; ++i) {
        int p = (w * 4 + i) * 64 + l;
        int r = p >> 3, cp = p & 7;
        int ar = r < 98 ? r : 97;
        aoff[i] = (long)ar * 256 + ((cp ^ (r & 7)) << 3);
        boff[i] = (long)(n0 + r) * 256 + ((cp ^ (r & 7)) << 3);
    }
    f4 acc[4][4];
    #pragma unroll
    for (int i = 0; i < 4; ++i)
        #pragma unroll
        for (int j = 0; j < 4; ++j) acc[i][j] = (f4){0.f, 0.f, 0.f, 0.f};

    for (int k0 = 0; k0 < 256; k0 += 64) {
        __syncthreads();
        #pragma unroll
        for (int i = 0; i < 4; ++i)
            GLDS16(Ab + aoff[i] + k0, &lsA[(w * 4 + i) * 512]);
        #pragma unroll
        for (int i = 0; i < 4; ++i)
            GLDS16(Bw + boff[i] + k0, &lsB[(w * 4 + i) * 512]);
        __syncthreads();
        #pragma unroll
        for (int kk = 0; kk < 2; ++kk) {
            s8v af[4], bf[4];
            #pragma unroll
            for (int mf = 0; mf < 4; ++mf) {
                int row = wr * 64 + mf * 16 + lq;
                int ph = (kk * 4 + g) ^ (row & 7);
                af[mf] = *(const s8v*)&lsA[row * 64 + ph * 8];
            }
            #pragma unroll
            for (int nf = 0; nf < 4; ++nf) {
                int row = wc * 64 + nf * 16 + lq;
                int ph = (kk * 4 + g) ^ (row & 7);
                bf[nf] = *(const s8v*)&lsB[row * 64 + ph * 8];
            }
            #pragma unroll
            for (int mf = 0; mf < 4; ++mf)
                #pragma unroll
                for (int nf = 0; nf < 4; ++nf)
                    acc[mf][nf] = __builtin_amdgcn_mfma_f32_16x16x32_bf16(
                        af[mf], bf[nf], acc[mf][nf], 0, 0, 0);
        }
    }
    #pragma unroll
    for (int mf = 0; mf < 4; ++mf)
        #pragma unroll
        for (int r = 0; r < 4; ++r) {
            int grow = wr * 64 + mf * 16 + g * 4 + r;   // 0..127
            #pragma unroll
            for (int nf = 0; nf < 4; ++nf) {
                int col = n0 + wc * 64 + nf * 16 + lq;
                u16 bv = (grow < 98) ? f2bf(acc[mf][nf][r]) : (u16)0;
                if (col < 256) {
                    if (grow < 112)
                        Kb[((size_t)(bz * 8 + (col >> 5)) * 112 + grow) * 32 + (col & 31)] = bv;
                } else {
                    int cc = col - 256;
                    Vtb[((size_t)(bz * 8 + (cc >> 5)) * 32 + (cc & 31)) * 128 + grow] = bv;
                }
            }
        }
}

// ---------------------------------------------------------------------------
// Fused attention + output projection. Grid (62, 8), 512 threads (8 waves).
// Round-10 proven version (64-row Q-tiles; 32-row split regressed: per-block
// fixed costs beat the TLP gain).
// ---------------------------------------------------------------------------
#define SCALE_F 0.1767766952966369f
__global__ __launch_bounds__(512) void attnout_kernel(
    const u16* __restrict__ Yq, const u16* __restrict__ Kb,
    const u16* __restrict__ Vtb, const u16* __restrict__ pwb,
    const float* __restrict__ proj_b, float* __restrict__ out)
{
    __shared__ u16 Ps[8][16 * 128];    // per-wave P scratch (4 KB each)
    __shared__ u16 Os[64 * 256];       // O panel, swizzled (32 KB)
    int tid = threadIdx.x;
    int w = tid >> 6, l = tid & 63, g = l >> 4, lq = l & 15;
    int b = blockIdx.y, h = w;
    int n0 = blockIdx.x * 64;
    const u16* Kh = Kb + (size_t)(b * 8 + h) * 112 * 32;
    const u16* Vh = Vtb + (size_t)(b * 8 + h) * 32 * 128;
    u16* Pw = Ps[w];

    // zero P pad granules 14,15 (keys 112..127) once
    if (l < 32) {
        int row = l >> 1;
        int gr = (14 + (l & 1)) ^ (row & 7);
        *(s8v*)&Pw[row * 128 + gr * 8] = (s8v){0, 0, 0, 0, 0, 0, 0, 0};
    }

    for (int qt = 0; qt < 4; ++qt) {
        int qrow = n0 + qt * 16 + lq;
        int qr = qrow < 3920 ? qrow : 3919;
        s8v qf = *(const s8v*)(Yq + ((size_t)b * 3920 + qr) * 256 + h * 32 + g * 8);
        f4 sacc[7];
        #pragma unroll
        for (int f = 0; f < 7; ++f) {
            s8v kf = *(const s8v*)(Kh + (f * 16 + lq) * 32 + g * 8);
            f4 zz = (f4){0.f, 0.f, 0.f, 0.f};
            sacc[f] = __builtin_amdgcn_mfma_f32_16x16x32_bf16(kf, qf, zz, 0, 0, 0);
        }
        float pm = -1e30f;
        float sv[7][4];
        #pragma unroll
        for (int f = 0; f < 7; ++f)
            #pragma unroll
            for (int r = 0; r < 4; ++r) {
                int key = f * 16 + g * 4 + r;
                float v = sacc[f][r] * SCALE_F;
                if (key >= 98) v = -1e30f;
                sv[f][r] = v;
                pm = fmaxf(pm, v);
            }
        pm = fmaxf(pm, __shfl_xor(pm, 16));
        pm = fmaxf(pm, __shfl_xor(pm, 32));
        float sum = 0.f;
        float pv[7][4];
        #pragma unroll
        for (int f = 0; f < 7; ++f)
            #pragma unroll
            for (int r = 0; r < 4; ++r) {
                float e = __expf(sv[f][r] - pm);
                pv[f][r] = e;
                sum += e;
            }
        sum += __shfl_xor(sum, 16);
        sum += __shfl_xor(sum, 32);
        float inv = 1.0f / sum;

        #pragma unroll
        for (int f = 0; f < 7; ++f)
            #pragma unroll
            for (int pr = 0; pr < 2; ++pr) {
                u32 pk = (u32)f2bf(pv[f][2 * pr] * inv) |
                         ((u32)f2bf(pv[f][2 * pr + 1] * inv) << 16);
                int k = f * 16 + g * 4 + pr * 2;
                int gr = (k >> 3) ^ (lq & 7);
                *(u32*)&Pw[lq * 128 + gr * 8 + (k & 7)] = pk;
            }

        f4 o0 = (f4){0.f, 0.f, 0.f, 0.f}, o1 = (f4){0.f, 0.f, 0.f, 0.f};
        #pragma unroll
        for (int s4 = 0; s4 < 4; ++s4) {
            int gv = s4 * 4 + g;
            s8v pa = *(const s8v*)&Pw[lq * 128 + ((gv ^ (lq & 7)) * 8)];
            s8v vf0 = *(const s8v*)(Vh + (size_t)lq * 128 + s4 * 32 + g * 8);
            s8v vf1 = *(const s8v*)(Vh + (size_t)(16 + lq) * 128 + s4 * 32 + g * 8);
            o0 = __builtin_amdgcn_mfma_f32_16x16x32_bf16(pa, vf0, o0, 0, 0, 0);
            o1 = __builtin_amdgcn_mfma_f32_16x16x32_bf16(pa, vf1, o1, 0, 0, 0);
        }
        #pragma unroll
        for (int r = 0; r < 4; ++r) {
            int R = qt * 16 + g * 4 + r;
            #pragma unroll
            for (int half = 0; half < 2; ++half) {
                int C = h * 32 + half * 16 + lq;
                int sg = (C >> 3) ^ (R & 7);
                Os[R * 256 + sg * 8 + (C & 7)] = f2bf(half ? o1[r] : o0[r]);
            }
        }
    }
    __syncthreads();

    // ---- out-proj: C[64 x 256] = O[64 x 256] * pwb^T + bias ----
    f4 acc[4][2];
    #pragma unroll
    for (int i = 0; i < 4; ++i) {
        acc[i][0] = (f4){0.f, 0.f, 0.f, 0.f};
        acc[i][1] = (f4){0.f, 0.f, 0.f, 0.f};
    }
    for (int k0 = 0; k0 < 256; k0 += 32) {
        s8v af[4], bf[2];
        int kgr = (k0 >> 3) + g;
        #pragma unroll
        for (int mf = 0; mf < 4; ++mf) {
            int row = mf * 16 + lq;
            af[mf] = *(const s8v*)&Os[row * 256 + ((kgr ^ (row & 7)) * 8)];
        }
        #pragma unroll
        for (int nf = 0; nf < 2; ++nf) {
            int n = w * 32 + nf * 16 + lq;
            bf[nf] = *(const s8v*)(pwb + (size_t)n * 256 + k0 + g * 8);
        }
        #pragma unroll
        for (int mf = 0; mf < 4; ++mf)
            #pragma unroll
            for (int nf = 0; nf < 2; ++nf)
                acc[mf][nf] = __builtin_amdgcn_mfma_f32_16x16x32_bf16(
                    af[mf], bf[nf], acc[mf][nf], 0, 0, 0);
    }
    #pragma unroll
    for (int mf = 0; mf < 4; ++mf)
        #pragma unroll
        for (int r = 0; r < 4; ++r) {
            int grow = n0 + mf * 16 + g * 4 + r;
            if (grow < 3920) {
                #pragma unroll
                for (int nf = 0; nf < 2; ++nf) {
                    int col = w * 32 + nf * 16 + lq;
                    out[((size_t)b * 3920 + grow) * 256 + col] = acc[mf][nf][r] + proj_b[col];
                }
            }
        }
}

// ---------------------------------------------------------------------------
extern "C" void kernel_launch(void* const* d_in, const int* in_sizes, int n_in,
                              void* d_out, int out_size, void* d_ws, size_t ws_size,
                              hipStream_t stream)
{
    const float* x0     = (const float*)d_in[0];
    const float* x1     = (const float*)d_in[1];
    const float* q_w    = (const float*)d_in[2];
    const float* kv_w   = (const float*)d_in[3];
    const float* proj_w = (const float*)d_in[4];
    const float* proj_b = (const float*)d_in[5];
    const float* sr0_w  = (const float*)d_in[6];
    const float* sr0_b  = (const float*)d_in[7];
    const float* sr1_w  = (const float*)d_in[8];
    const float* sr1_b  = (const float*)d_in[9];
    const float* n0w    = (const float*)d_in[10];
    const float* n0b    = (const float*)d_in[11];
    const float* n1w    = (const float*)d_in[12];
    const float* n1b    = (const float*)d_in[13];
    (void)in_sizes; (void)n_in; (void)out_size; (void)ws_size;

    float* ws = (float*)d_ws;
    u16*  Yq   = (u16*)ws;                         // [8][3920][256] bf16
    u16*  x0b  = (u16*)(ws + 4014080);             // [25088][256] bf16
    u16*  x1b  = (u16*)(ws + 7225344);             // [6272][256] bf16
    float* xr0 = ws + 8028160;                     // [16][392][256] fp32 slices
    float* xr1 = ws + 9633792;                     // [4][392][256]
    u16*  Kb   = (u16*)(ws + 10035200);            // [64][112][32] bf16
    u16*  Vtb  = (u16*)(ws + 10149888);            // [64][32][128] bf16
    u16*  qwb  = (u16*)(ws + 10280960);            // [256][256] bf16
    u16*  kvwb = (u16*)(ws + 10313728);            // [512][256] bf16
    u16*  pwb  = (u16*)(ws + 10379264);            // [256][256] bf16
    u16*  Wc0  = (u16*)(ws + 10412032);            // [256][16384] bf16
    u16*  Wc1  = (u16*)(ws + 12509184);            // [256][4096] bf16
    u16*  lnb  = (u16*)(ws + 13033472);            // [784][256] bf16

    // 1. fused converts + weight transposes
    prep_kernel<<<2048, 256, 0, stream>>>(
        x0, x1, q_w, kv_w, proj_w, sr0_w, sr1_w,
        x0b, x1b, qwb, kvwb, pwb, Wc0, Wc1);

    // 2. convs (long, first) + Q projection (short, backfill), one dispatch
    qc_kernel<<<656, 256, 0, stream>>>(x0b, x1b, qwb, Yq, Wc0, Wc1, xr0, xr1);

    // 3. layernorm (+conv bias, slice reduce) -> bf16, 784 blocks
    ln_kernel<<<784, 256, 0, stream>>>(xr0, xr1, sr0_b, sr1_b, n0w, n0b, n1w, n1b, lnb);

    // 4. KV projection -> Kb/Vtb (attnout layouts)
    kv_kernel<<<dim3(4, 1, 8), 256, 0, stream>>>(lnb, kvwb, Kb, Vtb);

    // 5. fused attention + output projection -> d_out fp32
    attnout_kernel<<<dim3(62, 8), 512, 0, stream>>>(
        Yq, Kb, Vtb, pwb, proj_b, (float*)d_out);
}

// Round 14
// 88.655 us; speedup vs baseline: 1.4155x; 1.2038x over previous
//
#include <hip/hip_runtime.h>

typedef unsigned short u16;
typedef unsigned int u32;
typedef float f4 __attribute__((ext_vector_type(4)));
typedef short s8v __attribute__((ext_vector_type(8)));
typedef unsigned short u16x4 __attribute__((ext_vector_type(4)));

__device__ __forceinline__ u16 f2bf(float f) {
    u32 u = __float_as_uint(f);
    u32 r = (u + 0x7FFFu + ((u >> 16) & 1u)) >> 16;
    return (u16)r;
}

#define GLDS16(g, l)                                                                   \
    __builtin_amdgcn_global_load_lds((const __attribute__((address_space(1))) u32*)(g),\
                                     (__attribute__((address_space(3))) u32*)(l), 16, 0, 0)

// ---------------------------------------------------------------------------
// Fused prep. bid 0..255: Wc0 transpose (one o each, LDS transpose, coalesced
// both sides). bid 256..511: Wc1 transpose. bid >= 512: flat fp32->bf16
// converts (grid-stride). One dispatch, zero math change vs round 13.
// ---------------------------------------------------------------------------
__global__ __launch_bounds__(256) void prep_kernel(
    const float* __restrict__ x0, const float* __restrict__ x1,
    const float* __restrict__ qw, const float* __restrict__ kvw,
    const float* __restrict__ pw, const float* __restrict__ w0,
    const float* __restrict__ w1,
    u16* __restrict__ x0b, u16* __restrict__ x1b, u16* __restrict__ qwb,
    u16* __restrict__ kvwb, u16* __restrict__ pwb,
    u16* __restrict__ Wc0, u16* __restrict__ Wc1)
{
    __shared__ u16 lds[64][264];
    int bid = blockIdx.x, t = threadIdx.x;
    if (bid < 256) {
        // ---- Wc0: w0[o][c][khw] (KHW=64) -> Wc0[o][khw*256 + c] ----
        const float* src = w0 + (size_t)bid * 16384;
        u16* dst = Wc0 + (size_t)bid * 16384;
        #pragma unroll
        for (int p = 0; p < 16; ++p) {
            int idx = p * 1024 + t * 4;          // = c*64 + khw
            f4 v = *(const f4*)(src + idx);      // 16B coalesced read
            int c_in = idx >> 6, khw_in = idx & 63;
            #pragma unroll
            for (int jj = 0; jj < 4; ++jj)
                lds[khw_in + jj][c_in] = f2bf(v[jj]);
        }
        __syncthreads();
        #pragma unroll
        for (int p = 0; p < 16; ++p) {
            int idx = p * 1024 + t * 4;          // = khw*256 + c
            int khw = idx >> 8, c = idx & 255;
            u16x4 ov;
            ov[0] = lds[khw][c + 0]; ov[1] = lds[khw][c + 1];
            ov[2] = lds[khw][c + 2]; ov[3] = lds[khw][c + 3];
            *(u16x4*)(dst + idx) = ov;           // 8B coalesced write
        }
    } else if (bid < 512) {
        // ---- Wc1: w1[o][c][khw] (KHW=16) -> Wc1[o][khw*256 + c] ----
        int o = bid - 256;
        const float* src = w1 + (size_t)o * 4096;
        u16* dst = Wc1 + (size_t)o * 4096;
        #pragma unroll
        for (int p = 0; p < 4; ++p) {
            int idx = p * 1024 + t * 4;          // = c*16 + khw
            f4 v = *(const f4*)(src + idx);
            int c_in = idx >> 4, khw_in = idx & 15;
            #pragma unroll
            for (int jj = 0; jj < 4; ++jj)
                lds[khw_in + jj][c_in] = f2bf(v[jj]);
        }
        __syncthreads();
        #pragma unroll
        for (int p = 0; p < 4; ++p) {
            int idx = p * 1024 + t * 4;          // = khw*256 + c
            int khw = idx >> 8, c = idx & 255;
            u16x4 ov;
            ov[0] = lds[khw][c + 0]; ov[1] = lds[khw][c + 1];
            ov[2] = lds[khw][c + 2]; ov[3] = lds[khw][c + 3];
            *(u16x4*)(dst + idx) = ov;
        }
    } else {
        // ---- flat converts: units [0, 2072576) of 4 elements each ----
        for (int u = (bid - 512) * 256 + t; u < 2072576; u += 1536 * 256) {
            const float* src; u16* dst; int idx;
            if (u < 1605632)      { src = x0;  dst = x0b;  idx = u; }
            else if (u < 2007040) { src = x1;  dst = x1b;  idx = u - 1605632; }
            else if (u < 2023424) { src = qw;  dst = qwb;  idx = u - 2007040; }
            else if (u < 2056192) { src = kvw; dst = kvwb; idx = u - 2023424; }
            else                  { src = pw;  dst = pwb;  idx = u - 2056192; }
            f4 v = *(const f4*)(src + (size_t)idx * 4);
            u16x4 o;
            o[0] = f2bf(v[0]); o[1] = f2bf(v[1]); o[2] = f2bf(v[2]); o[3] = f2bf(v[3]);
            *(u16x4*)(dst + (size_t)idx * 4) = o;
        }
    }
}

// ---------------------------------------------------------------------------
// Merged conv + Q-projection dispatch, LPT-ordered: conv tiles (4x longer,
// K=1024) are bid 0..159 so they start at t=0; qproj tiles (K=256) backfill.
// conv: split-K slice buffers (Ksl=1024, no atomics).
// ---------------------------------------------------------------------------
__global__ __launch_bounds__(256) void qc_kernel(
    const u16* __restrict__ x0b, const u16* __restrict__ x1b,
    const u16* __restrict__ qwb, u16* __restrict__ Yq,
    const u16* __restrict__ Wc0, const u16* __restrict__ Wc1,
    float* __restrict__ xr0, float* __restrict__ xr1)
{
    __shared__ u16 lsA[128 * 64];
    __shared__ u16 lsB[128 * 64];
    int bid = blockIdx.x;
    int tid = threadIdx.x;
    int w = tid >> 6, l = tid & 63, g = l >> 4, lq = l & 15;
    int wr = w >> 1, wc = w & 1;

    f4 acc[4][4];
    #pragma unroll
    for (int i = 0; i < 4; ++i)
        #pragma unroll
        for (int j = 0; j < 4; ++j) acc[i][j] = (f4){0.f, 0.f, 0.f, 0.f};

    if (bid >= 160) {
        // ------------------- Q projection (short blocks, backfill) ---------
        int bid2 = bid - 160;
        int x = bid2 & 1, y = (bid2 >> 1) % 31, bz = bid2 / 62;
        int m0 = y * 128, n0 = x * 128;
        const u16* aptr[4];
        long boff[4];
        #pragma unroll
        for (int i = 0; i < 4; ++i) {
            int p = (w * 4 + i) * 64 + l;
            int r = p >> 3, cp = p & 7;
            int ar = m0 + r; ar = ar < 3920 ? ar : 3919;
            const u16* base = (ar < 3136)
                ? x0b + ((size_t)bz * 3136 + ar) * 256
                : x1b + ((size_t)bz * 784 + (ar - 3136)) * 256;
            aptr[i] = base + ((cp ^ (r & 7)) << 3);
            boff[i] = (long)(n0 + r) * 256 + ((cp ^ (r & 7)) << 3);
        }
        for (int k0 = 0; k0 < 256; k0 += 64) {
            __syncthreads();
            #pragma unroll
            for (int i = 0; i < 4; ++i)
                GLDS16(aptr[i] + k0, &lsA[(w * 4 + i) * 512]);
            #pragma unroll
            for (int i = 0; i < 4; ++i)
                GLDS16(qwb + boff[i] + k0, &lsB[(w * 4 + i) * 512]);
            __syncthreads();
            #pragma unroll
            for (int kk = 0; kk < 2; ++kk) {
                s8v af[4], bf[4];
                #pragma unroll
                for (int mf = 0; mf < 4; ++mf) {
                    int row = wr * 64 + mf * 16 + lq;
                    int ph = (kk * 4 + g) ^ (row & 7);
                    af[mf] = *(const s8v*)&lsA[row * 64 + ph * 8];
                }
                #pragma unroll
                for (int nf = 0; nf < 4; ++nf) {
                    int row = wc * 64 + nf * 16 + lq;
                    int ph = (kk * 4 + g) ^ (row & 7);
                    bf[nf] = *(const s8v*)&lsB[row * 64 + ph * 8];
                }
                #pragma unroll
                for (int mf = 0; mf < 4; ++mf)
                    #pragma unroll
                    for (int nf = 0; nf < 4; ++nf)
                        acc[mf][nf] = __builtin_amdgcn_mfma_f32_16x16x32_bf16(
                            af[mf], bf[nf], acc[mf][nf], 0, 0, 0);
            }
        }
        #pragma unroll
        for (int mf = 0; mf < 4; ++mf)
            #pragma unroll
            for (int r = 0; r < 4; ++r) {
                int grow = m0 + wr * 64 + mf * 16 + g * 4 + r;
                if (grow < 3920) {
                    #pragma unroll
                    for (int nf = 0; nf < 4; ++nf) {
                        int col = n0 + wc * 64 + nf * 16 + lq;
                        Yq[((size_t)bz * 3920 + grow) * 256 + col] = f2bf(acc[mf][nf][r]);
                    }
                }
            }
    } else {
        // ------------------- conv (long blocks, start first) ---------------
        int cb = bid;
        int bx = cb & 1, by = (cb >> 1) & 3, z = cb >> 3;
        const u16* Xb; const u16* Wcp; float* Co;
        int Npix, Wimg, lgs, Kc, zz;
        if (z < 16) { Xb = x0b; Wcp = Wc0; Co = xr0; Npix = 3136; Wimg = 56; lgs = 3; Kc = 16384; zz = z; }
        else        { Xb = x1b; Wcp = Wc1; Co = xr1; Npix = 784;  Wimg = 28; lgs = 2; Kc = 4096;  zz = z - 16; }
        int s = 1 << lgs;
        int m0 = by * 128, n0 = bx * 128;

        long aoff[4], boff[4];
        #pragma unroll
        for (int i = 0; i < 4; ++i) {
            int p = (w * 4 + i) * 64 + l;
            int r = p >> 3, cp = p & 7;
            int rr = m0 + r; rr = rr < 392 ? rr : 391;
            int bb = rr / 49, pp = rr % 49;
            int ph = pp / 7, pw = pp % 7;
            aoff[i] = ((long)bb * Npix + (long)(ph * Wimg + pw) * s) * 256 + ((cp ^ (r & 7)) << 3);
            boff[i] = (long)(n0 + r) * Kc + ((cp ^ (r & 7)) << 3);
        }
        int kbase = zz * 1024;
        for (int ko = 0; ko < 1024; ko += 64) {
            int k0 = kbase + ko;
            int khw = k0 >> 8;
            int kh = khw >> lgs, kw = khw & (s - 1);
            long adelta = (long)(kh * Wimg + kw) * 256 + (k0 & 255);
            __syncthreads();
            #pragma unroll
            for (int i = 0; i < 4; ++i)
                GLDS16(Xb + aoff[i] + adelta, &lsA[(w * 4 + i) * 512]);
            #pragma unroll
            for (int i = 0; i < 4; ++i)
                GLDS16(Wcp + boff[i] + k0, &lsB[(w * 4 + i) * 512]);
            __syncthreads();
            #pragma unroll
            for (int kk = 0; kk < 2; ++kk) {
                s8v af[4], bf[4];
                #pragma unroll
                for (int mf = 0; mf < 4; ++mf) {
                    int row = wr * 64 + mf * 16 + lq;
                    int ph2 = (kk * 4 + g) ^ (row & 7);
                    af[mf] = *(const s8v*)&lsA[row * 64 + ph2 * 8];
                }
                #pragma unroll
                for (int nf = 0; nf < 4; ++nf) {
                    int row = wc * 64 + nf * 16 + lq;
                    int ph2 = (kk * 4 + g) ^ (row & 7);
                    bf[nf] = *(const s8v*)&lsB[row * 64 + ph2 * 8];
                }
                #pragma unroll
                for (int mf = 0; mf < 4; ++mf)
                    #pragma unroll
                    for (int nf = 0; nf < 4; ++nf)
                        acc[mf][nf] = __builtin_amdgcn_mfma_f32_16x16x32_bf16(
                            af[mf], bf[nf], acc[mf][nf], 0, 0, 0);
            }
        }
        float* Cb = Co + (size_t)zz * 392 * 256;
        #pragma unroll
        for (int mf = 0; mf < 4; ++mf)
            #pragma unroll
            for (int r = 0; r < 4; ++r) {
                int grow = m0 + wr * 64 + mf * 16 + g * 4 + r;
                if (grow < 392) {
                    #pragma unroll
                    for (int nf = 0; nf < 4; ++nf) {
                        int col = n0 + wc * 64 + nf * 16 + lq;
                        Cb[(size_t)grow * 256 + col] = acc[mf][nf][r];
                    }
                }
            }
    }
}

// ---------------------------------------------------------------------------
// LayerNorm: sum conv slices (16 / 4) + conv bias, normalize, write bf16.
// ---------------------------------------------------------------------------
__global__ __launch_bounds__(256) void ln_kernel(
    const float* __restrict__ xr0, const float* __restrict__ xr1,
    const float* __restrict__ srb0, const float* __restrict__ srb1,
    const float* __restrict__ n0w, const float* __restrict__ n0b,
    const float* __restrict__ n1w, const float* __restrict__ n1b,
    u16* __restrict__ lnb)
{
    int row = blockIdx.x;            // 0..783
    int b = row / 98, j = row % 98;
    int c = threadIdx.x;
    const float* src; int sidx, ns;
    const float *bs, *nw, *nb;
    if (j < 49) { src = xr0; sidx = b * 49 + j;       ns = 16; bs = srb0; nw = n0w; nb = n0b; }
    else        { src = xr1; sidx = b * 49 + (j - 49); ns = 4; bs = srb1; nw = n1w; nb = n1b; }
    float v = bs[c];
    for (int sl = 0; sl < ns; ++sl) v += src[(size_t)sl * 100352 + (size_t)sidx * 256 + c];
    __shared__ float red[8];
    float sumv = v;
    #pragma unroll
    for (int off = 32; off; off >>= 1) sumv += __shfl_down(sumv, off, 64);
    int wid = c >> 6, lane = c & 63;
    if (lane == 0) red[wid] = sumv;
    __syncthreads();
    float mu = (red[0] + red[1] + red[2] + red[3]) * (1.0f / 256.0f);
    float dv = v - mu;
    float s2 = dv * dv;
    #pragma unroll
    for (int off = 32; off; off >>= 1) s2 += __shfl_down(s2, off, 64);
    if (lane == 0) red[4 + wid] = s2;
    __syncthreads();
    float var = (red[4] + red[5] + red[6] + red[7]) * (1.0f / 256.0f);
    float rr = rsqrtf(var + 1e-5f);
    lnb[(size_t)row * 256 + c] = f2bf(dv * rr * nw[c] + nb[c]);
}

// ---------------------------------------------------------------------------
// KV projection -> Kb[bh][112][32] (rows>=98 zero), Vtb[bh][32][128]
// (cols>=98 zero). Grid (4, 1, 8).
// ---------------------------------------------------------------------------
__global__ __launch_bounds__(256) void kv_kernel(
    const u16* __restrict__ A, const u16* __restrict__ Bw,
    u16* __restrict__ Kb, u16* __restrict__ Vtb)
{
    __shared__ u16 lsA[128 * 64];
    __shared__ u16 lsB[128 * 64];
    int tid = threadIdx.x;
    int w = tid >> 6, l = tid & 63, g = l >> 4, lq = l & 15;
    int wr = w >> 1, wc = w & 1;
    int n0 = blockIdx.x * 128;
    int bz = blockIdx.z;
    const u16* Ab = A + (size_t)bz * 98 * 256;

    long aoff[4], boff[4];
    #pragma unroll
    for (int i = 0; i < 4; ++i) {
        int p = (w * 4 + i) * 64 + l;
        int r = p >> 3, cp = p & 7;
        int ar = r < 98 ? r : 97;
        aoff[i] = (long)ar * 256 + ((cp ^ (r & 7)) << 3);
        boff[i] = (long)(n0 + r) * 256 + ((cp ^ (r & 7)) << 3);
    }
    f4 acc[4][4];
    #pragma unroll
    for (int i = 0; i < 4; ++i)
        #pragma unroll
        for (int j = 0; j < 4; ++j) acc[i][j] = (f4){0.f, 0.f, 0.f, 0.f};

    for (int k0 = 0; k0 < 256; k0 += 64) {
        __syncthreads();
        #pragma unroll
        for (int i = 0; i < 4; ++i)
            GLDS16(Ab + aoff[i] + k0, &lsA[(w * 4 + i) * 512]);
        #pragma unroll
        for (int i = 0; i < 4; ++i)
            GLDS16(Bw + boff[i] + k0, &lsB[(w * 4 + i) * 512]);
        __syncthreads();
        #pragma unroll
        for (int kk = 0; kk < 2; ++kk) {
            s8v af[4], bf[4];
            #pragma unroll
            for (int mf = 0; mf < 4; ++mf) {
                int row = wr * 64 + mf * 16 + lq;
                int ph = (kk * 4 + g) ^ (row & 7);
                af[mf] = *(const s8v*)&lsA[row * 64 + ph * 8];
            }
            #pragma unroll
            for (int nf = 0; nf < 4; ++nf) {
                int row = wc * 64 + nf * 16 + lq;
                int ph = (kk * 4 + g) ^ (row & 7);
                bf[nf] = *(const s8v*)&lsB[row * 64 + ph * 8];
            }
            #pragma unroll
            for (int mf = 0; mf < 4; ++mf)
                #pragma unroll
                for (int nf = 0; nf < 4; ++nf)
                    acc[mf][nf] = __builtin_amdgcn_mfma_f32_16x16x32_bf16(
                        af[mf], bf[nf], acc[mf][nf], 0, 0, 0);
        }
    }
    #pragma unroll
    for (int mf = 0; mf < 4; ++mf)
        #pragma unroll
        for (int r = 0; r < 4; ++r) {
            int grow = wr * 64 + mf * 16 + g * 4 + r;   // 0..127
            #pragma unroll
            for (int nf = 0; nf < 4; ++nf) {
                int col = n0 + wc * 64 + nf * 16 + lq;
                u16 bv = (grow < 98) ? f2bf(acc[mf][nf][r]) : (u16)0;
                if (col < 256) {
                    if (grow < 112)
                        Kb[((size_t)(bz * 8 + (col >> 5)) * 112 + grow) * 32 + (col & 31)] = bv;
                } else {
                    int cc = col - 256;
                    Vtb[((size_t)(bz * 8 + (cc >> 5)) * 32 + (cc & 31)) * 128 + grow] = bv;
                }
            }
        }
}

// ---------------------------------------------------------------------------
// Fused attention + output projection. Grid (62, 8), 512 threads (8 waves).
// Round-10 proven version (64-row Q-tiles).
// ---------------------------------------------------------------------------
#define SCALE_F 0.1767766952966369f
__global__ __launch_bounds__(512) void attnout_kernel(
    const u16* __restrict__ Yq, const u16* __restrict__ Kb,
    const u16* __restrict__ Vtb, const u16* __restrict__ pwb,
    const float* __restrict__ proj_b, float* __restrict__ out)
{
    __shared__ u16 Ps[8][16 * 128];    // per-wave P scratch (4 KB each)
    __shared__ u16 Os[64 * 256];       // O panel, swizzled (32 KB)
    int tid = threadIdx.x;
    int w = tid >> 6, l = tid & 63, g = l >> 4, lq = l & 15;
    int b = blockIdx.y, h = w;
    int n0 = blockIdx.x * 64;
    const u16* Kh = Kb + (size_t)(b * 8 + h) * 112 * 32;
    const u16* Vh = Vtb + (size_t)(b * 8 + h) * 32 * 128;
    u16* Pw = Ps[w];

    // zero P pad granules 14,15 (keys 112..127) once
    if (l < 32) {
        int row = l >> 1;
        int gr = (14 + (l & 1)) ^ (row & 7);
        *(s8v*)&Pw[row * 128 + gr * 8] = (s8v){0, 0, 0, 0, 0, 0, 0, 0};
    }

    for (int qt = 0; qt < 4; ++qt) {
        int qrow = n0 + qt * 16 + lq;
        int qr = qrow < 3920 ? qrow : 3919;
        s8v qf = *(const s8v*)(Yq + ((size_t)b * 3920 + qr) * 256 + h * 32 + g * 8);
        f4 sacc[7];
        #pragma unroll
        for (int f = 0; f < 7; ++f) {
            s8v kf = *(const s8v*)(Kh + (f * 16 + lq) * 32 + g * 8);
            f4 zz = (f4){0.f, 0.f, 0.f, 0.f};
            sacc[f] = __builtin_amdgcn_mfma_f32_16x16x32_bf16(kf, qf, zz, 0, 0, 0);
        }
        float pm = -1e30f;
        float sv[7][4];
        #pragma unroll
        for (int f = 0; f < 7; ++f)
            #pragma unroll
            for (int r = 0; r < 4; ++r) {
                int key = f * 16 + g * 4 + r;
                float v = sacc[f][r] * SCALE_F;
                if (key >= 98) v = -1e30f;
                sv[f][r] = v;
                pm = fmaxf(pm, v);
            }
        pm = fmaxf(pm, __shfl_xor(pm, 16));
        pm = fmaxf(pm, __shfl_xor(pm, 32));
        float sum = 0.f;
        float pv[7][4];
        #pragma unroll
        for (int f = 0; f < 7; ++f)
            #pragma unroll
            for (int r = 0; r < 4; ++r) {
                float e = __expf(sv[f][r] - pm);
                pv[f][r] = e;
                sum += e;
            }
        sum += __shfl_xor(sum, 16);
        sum += __shfl_xor(sum, 32);
        float inv = 1.0f / sum;

        #pragma unroll
        for (int f = 0; f < 7; ++f)
            #pragma unroll
            for (int pr = 0; pr < 2; ++pr) {
                u32 pk = (u32)f2bf(pv[f][2 * pr] * inv) |
                         ((u32)f2bf(pv[f][2 * pr + 1] * inv) << 16);
                int k = f * 16 + g * 4 + pr * 2;
                int gr = (k >> 3) ^ (lq & 7);
                *(u32*)&Pw[lq * 128 + gr * 8 + (k & 7)] = pk;
            }

        f4 o0 = (f4){0.f, 0.f, 0.f, 0.f}, o1 = (f4){0.f, 0.f, 0.f, 0.f};
        #pragma unroll
        for (int s4 = 0; s4 < 4; ++s4) {
            int gv = s4 * 4 + g;
            s8v pa = *(const s8v*)&Pw[lq * 128 + ((gv ^ (lq & 7)) * 8)];
            s8v vf0 = *(const s8v*)(Vh + (size_t)lq * 128 + s4 * 32 + g * 8);
            s8v vf1 = *(const s8v*)(Vh + (size_t)(16 + lq) * 128 + s4 * 32 + g * 8);
            o0 = __builtin_amdgcn_mfma_f32_16x16x32_bf16(pa, vf0, o0, 0, 0, 0);
            o1 = __builtin_amdgcn_mfma_f32_16x16x32_bf16(pa, vf1, o1, 0, 0, 0);
        }
        #pragma unroll
        for (int r = 0; r < 4; ++r) {
            int R = qt * 16 + g * 4 + r;
            #pragma unroll
            for (int half = 0; half < 2; ++half) {
                int C = h * 32 + half * 16 + lq;
                int sg = (C >> 3) ^ (R & 7);
                Os[R * 256 + sg * 8 + (C & 7)] = f2bf(half ? o1[r] : o0[r]);
            }
        }
    }
    __syncthreads();

    // ---- out-proj: C[64 x 256] = O[64 x 256] * pwb^T + bias ----
    f4 acc[4][2];
    #pragma unroll
    for (int i = 0; i < 4; ++i) {
        acc[i][0] = (f4){0.f, 0.f, 0.f, 0.f};
        acc[i][1] = (f4){0.f, 0.f, 0.f, 0.f};
    }
    for (int k0 = 0; k0 < 256; k0 += 32) {
        s8v af[4], bf[2];
        int kgr = (k0 >> 3) + g;
        #pragma unroll
        for (int mf = 0; mf < 4; ++mf) {
            int row = mf * 16 + lq;
            af[mf] = *(const s8v*)&Os[row * 256 + ((kgr ^ (row & 7)) * 8)];
        }
        #pragma unroll
        for (int nf = 0; nf < 2; ++nf) {
            int n = w * 32 + nf * 16 + lq;
            bf[nf] = *(const s8v*)(pwb + (size_t)n * 256 + k0 + g * 8);
        }
        #pragma unroll
        for (int mf = 0; mf < 4; ++mf)
            #pragma unroll
            for (int nf = 0; nf < 2; ++nf)
                acc[mf][nf] = __builtin_amdgcn_mfma_f32_16x16x32_bf16(
                    af[mf], bf[nf], acc[mf][nf], 0, 0, 0);
    }
    #pragma unroll
    for (int mf = 0; mf < 4; ++mf)
        #pragma unroll
        for (int r = 0; r < 4; ++r) {
            int grow = n0 + mf * 16 + g * 4 + r;
            if (grow < 3920) {
                #pragma unroll
                for (int nf = 0; nf < 2; ++nf) {
                    int col = w * 32 + nf * 16 + lq;
                    out[((size_t)b * 3920 + grow) * 256 + col] = acc[mf][nf][r] + proj_b[col];
                }
            }
        }
}

// ---------------------------------------------------------------------------
extern "C" void kernel_launch(void* const* d_in, const int* in_sizes, int n_in,
                              void* d_out, int out_size, void* d_ws, size_t ws_size,
                              hipStream_t stream)
{
    const float* x0     = (const float*)d_in[0];
    const float* x1     = (const float*)d_in[1];
    const float* q_w    = (const float*)d_in[2];
    const float* kv_w   = (const float*)d_in[3];
    const float* proj_w = (const float*)d_in[4];
    const float* proj_b = (const float*)d_in[5];
    const float* sr0_w  = (const float*)d_in[6];
    const float* sr0_b  = (const float*)d_in[7];
    const float* sr1_w  = (const float*)d_in[8];
    const float* sr1_b  = (const float*)d_in[9];
    const float* n0w    = (const float*)d_in[10];
    const float* n0b    = (const float*)d_in[11];
    const float* n1w    = (const float*)d_in[12];
    const float* n1b    = (const float*)d_in[13];
    (void)in_sizes; (void)n_in; (void)out_size; (void)ws_size;

    float* ws = (float*)d_ws;
    u16*  Yq   = (u16*)ws;                         // [8][3920][256] bf16
    u16*  x0b  = (u16*)(ws + 4014080);             // [25088][256] bf16
    u16*  x1b  = (u16*)(ws + 7225344);             // [6272][256] bf16
    float* xr0 = ws + 8028160;                     // [16][392][256] fp32 slices
    float* xr1 = ws + 9633792;                     // [4][392][256]
    u16*  Kb   = (u16*)(ws + 10035200);            // [64][112][32] bf16
    u16*  Vtb  = (u16*)(ws + 10149888);            // [64][32][128] bf16
    u16*  qwb  = (u16*)(ws + 10280960);            // [256][256] bf16
    u16*  kvwb = (u16*)(ws + 10313728);            // [512][256] bf16
    u16*  pwb  = (u16*)(ws + 10379264);            // [256][256] bf16
    u16*  Wc0  = (u16*)(ws + 10412032);            // [256][16384] bf16
    u16*  Wc1  = (u16*)(ws + 12509184);            // [256][4096] bf16
    u16*  lnb  = (u16*)(ws + 13033472);            // [784][256] bf16

    // 1. fused prep: LDS-transposed conv weights + flat converts
    prep_kernel<<<2048, 256, 0, stream>>>(
        x0, x1, q_w, kv_w, proj_w, sr0_w, sr1_w,
        x0b, x1b, qwb, kvwb, pwb, Wc0, Wc1);

    // 2. convs (long, first) + Q projection (short, backfill), one dispatch
    qc_kernel<<<656, 256, 0, stream>>>(x0b, x1b, qwb, Yq, Wc0, Wc1, xr0, xr1);

    // 3. layernorm (+conv bias, slice reduce) -> bf16, 784 blocks
    ln_kernel<<<784, 256, 0, stream>>>(xr0, xr1, sr0_b, sr1_b, n0w, n0b, n1w, n1b, lnb);

    // 4. KV projection -> Kb/Vtb (attnout layouts)
    kv_kernel<<<dim3(4, 1, 8), 256, 0, stream>>>(lnb, kvwb, Kb, Vtb);

    // 5. fused attention + output projection -> d_out fp32
    attnout_kernel<<<dim3(62, 8), 512, 0, stream>>>(
        Yq, Kb, Vtb, pwb, proj_b, (float*)d_out);
}

// Round 15
// 88.335 us; speedup vs baseline: 1.4207x; 1.0036x over previous
//
#include <hip/hip_runtime.h>

typedef unsigned short u16;
typedef unsigned int u32;
typedef float f4 __attribute__((ext_vector_type(4)));
typedef short s8v __attribute__((ext_vector_type(8)));
typedef unsigned short u16x4 __attribute__((ext_vector_type(4)));

__device__ __forceinline__ u16 f2bf(float f) {
    u32 u = __float_as_uint(f);
    u32 r = (u + 0x7FFFu + ((u >> 16) & 1u)) >> 16;
    return (u16)r;
}

#define GLDS16(g, l)                                                                   \
    __builtin_amdgcn_global_load_lds((const __attribute__((address_space(1))) u32*)(g),\
                                     (__attribute__((address_space(3))) u32*)(l), 16, 0, 0)

// ---------------------------------------------------------------------------
// Fused prep. bid 0..255: Wc0 transpose (LDS transpose, coalesced both sides).
// bid 256..511: Wc1 transpose. bid >= 512: flat fp32->bf16 converts.
// ---------------------------------------------------------------------------
__global__ __launch_bounds__(256) void prep_kernel(
    const float* __restrict__ x0, const float* __restrict__ x1,
    const float* __restrict__ qw, const float* __restrict__ kvw,
    const float* __restrict__ pw, const float* __restrict__ w0,
    const float* __restrict__ w1,
    u16* __restrict__ x0b, u16* __restrict__ x1b, u16* __restrict__ qwb,
    u16* __restrict__ kvwb, u16* __restrict__ pwb,
    u16* __restrict__ Wc0, u16* __restrict__ Wc1)
{
    __shared__ u16 lds[64][264];
    int bid = blockIdx.x, t = threadIdx.x;
    if (bid < 256) {
        const float* src = w0 + (size_t)bid * 16384;
        u16* dst = Wc0 + (size_t)bid * 16384;
        #pragma unroll
        for (int p = 0; p < 16; ++p) {
            int idx = p * 1024 + t * 4;          // = c*64 + khw
            f4 v = *(const f4*)(src + idx);
            int c_in = idx >> 6, khw_in = idx & 63;
            #pragma unroll
            for (int jj = 0; jj < 4; ++jj)
                lds[khw_in + jj][c_in] = f2bf(v[jj]);
        }
        __syncthreads();
        #pragma unroll
        for (int p = 0; p < 16; ++p) {
            int idx = p * 1024 + t * 4;          // = khw*256 + c
            int khw = idx >> 8, c = idx & 255;
            u16x4 ov;
            ov[0] = lds[khw][c + 0]; ov[1] = lds[khw][c + 1];
            ov[2] = lds[khw][c + 2]; ov[3] = lds[khw][c + 3];
            *(u16x4*)(dst + idx) = ov;
        }
    } else if (bid < 512) {
        int o = bid - 256;
        const float* src = w1 + (size_t)o * 4096;
        u16* dst = Wc1 + (size_t)o * 4096;
        #pragma unroll
        for (int p = 0; p < 4; ++p) {
            int idx = p * 1024 + t * 4;          // = c*16 + khw
            f4 v = *(const f4*)(src + idx);
            int c_in = idx >> 4, khw_in = idx & 15;
            #pragma unroll
            for (int jj = 0; jj < 4; ++jj)
                lds[khw_in + jj][c_in] = f2bf(v[jj]);
        }
        __syncthreads();
        #pragma unroll
        for (int p = 0; p < 4; ++p) {
            int idx = p * 1024 + t * 4;          // = khw*256 + c
            int khw = idx >> 8, c = idx & 255;
            u16x4 ov;
            ov[0] = lds[khw][c + 0]; ov[1] = lds[khw][c + 1];
            ov[2] = lds[khw][c + 2]; ov[3] = lds[khw][c + 3];
            *(u16x4*)(dst + idx) = ov;
        }
    } else {
        for (int u = (bid - 512) * 256 + t; u < 2072576; u += 1536 * 256) {
            const float* src; u16* dst; int idx;
            if (u < 1605632)      { src = x0;  dst = x0b;  idx = u; }
            else if (u < 2007040) { src = x1;  dst = x1b;  idx = u - 1605632; }
            else if (u < 2023424) { src = qw;  dst = qwb;  idx = u - 2007040; }
            else if (u < 2056192) { src = kvw; dst = kvwb; idx = u - 2023424; }
            else                  { src = pw;  dst = pwb;  idx = u - 2056192; }
            f4 v = *(const f4*)(src + (size_t)idx * 4);
            u16x4 o;
            o[0] = f2bf(v[0]); o[1] = f2bf(v[1]); o[2] = f2bf(v[2]); o[3] = f2bf(v[3]);
            *(u16x4*)(dst + (size_t)idx * 4) = o;
        }
    }
}

// ---------------------------------------------------------------------------
// Merged conv + Q-projection dispatch, LPT-ordered (conv first).
// ---------------------------------------------------------------------------
__global__ __launch_bounds__(256) void qc_kernel(
    const u16* __restrict__ x0b, const u16* __restrict__ x1b,
    const u16* __restrict__ qwb, u16* __restrict__ Yq,
    const u16* __restrict__ Wc0, const u16* __restrict__ Wc1,
    float* __restrict__ xr0, float* __restrict__ xr1)
{
    __shared__ u16 lsA[128 * 64];
    __shared__ u16 lsB[128 * 64];
    int bid = blockIdx.x;
    int tid = threadIdx.x;
    int w = tid >> 6, l = tid & 63, g = l >> 4, lq = l & 15;
    int wr = w >> 1, wc = w & 1;

    f4 acc[4][4];
    #pragma unroll
    for (int i = 0; i < 4; ++i)
        #pragma unroll
        for (int j = 0; j < 4; ++j) acc[i][j] = (f4){0.f, 0.f, 0.f, 0.f};

    if (bid >= 160) {
        int bid2 = bid - 160;
        int x = bid2 & 1, y = (bid2 >> 1) % 31, bz = bid2 / 62;
        int m0 = y * 128, n0 = x * 128;
        const u16* aptr[4];
        long boff[4];
        #pragma unroll
        for (int i = 0; i < 4; ++i) {
            int p = (w * 4 + i) * 64 + l;
            int r = p >> 3, cp = p & 7;
            int ar = m0 + r; ar = ar < 3920 ? ar : 3919;
            const u16* base = (ar < 3136)
                ? x0b + ((size_t)bz * 3136 + ar) * 256
                : x1b + ((size_t)bz * 784 + (ar - 3136)) * 256;
            aptr[i] = base + ((cp ^ (r & 7)) << 3);
            boff[i] = (long)(n0 + r) * 256 + ((cp ^ (r & 7)) << 3);
        }
        for (int k0 = 0; k0 < 256; k0 += 64) {
            __syncthreads();
            #pragma unroll
            for (int i = 0; i < 4; ++i)
                GLDS16(aptr[i] + k0, &lsA[(w * 4 + i) * 512]);
            #pragma unroll
            for (int i = 0; i < 4; ++i)
                GLDS16(qwb + boff[i] + k0, &lsB[(w * 4 + i) * 512]);
            __syncthreads();
            #pragma unroll
            for (int kk = 0; kk < 2; ++kk) {
                s8v af[4], bf[4];
                #pragma unroll
                for (int mf = 0; mf < 4; ++mf) {
                    int row = wr * 64 + mf * 16 + lq;
                    int ph = (kk * 4 + g) ^ (row & 7);
                    af[mf] = *(const s8v*)&lsA[row * 64 + ph * 8];
                }
                #pragma unroll
                for (int nf = 0; nf < 4; ++nf) {
                    int row = wc * 64 + nf * 16 + lq;
                    int ph = (kk * 4 + g) ^ (row & 7);
                    bf[nf] = *(const s8v*)&lsB[row * 64 + ph * 8];
                }
                #pragma unroll
                for (int mf = 0; mf < 4; ++mf)
                    #pragma unroll
                    for (int nf = 0; nf < 4; ++nf)
                        acc[mf][nf] = __builtin_amdgcn_mfma_f32_16x16x32_bf16(
                            af[mf], bf[nf], acc[mf][nf], 0, 0, 0);
            }
        }
        #pragma unroll
        for (int mf = 0; mf < 4; ++mf)
            #pragma unroll
            for (int r = 0; r < 4; ++r) {
                int grow = m0 + wr * 64 + mf * 16 + g * 4 + r;
                if (grow < 3920) {
                    #pragma unroll
                    for (int nf = 0; nf < 4; ++nf) {
                        int col = n0 + wc * 64 + nf * 16 + lq;
                        Yq[((size_t)bz * 3920 + grow) * 256 + col] = f2bf(acc[mf][nf][r]);
                    }
                }
            }
    } else {
        int cb = bid;
        int bx = cb & 1, by = (cb >> 1) & 3, z = cb >> 3;
        const u16* Xb; const u16* Wcp; float* Co;
        int Npix, Wimg, lgs, Kc, zz;
        if (z < 16) { Xb = x0b; Wcp = Wc0; Co = xr0; Npix = 3136; Wimg = 56; lgs = 3; Kc = 16384; zz = z; }
        else        { Xb = x1b; Wcp = Wc1; Co = xr1; Npix = 784;  Wimg = 28; lgs = 2; Kc = 4096;  zz = z - 16; }
        int s = 1 << lgs;
        int m0 = by * 128, n0 = bx * 128;

        long aoff[4], boff[4];
        #pragma unroll
        for (int i = 0; i < 4; ++i) {
            int p = (w * 4 + i) * 64 + l;
            int r = p >> 3, cp = p & 7;
            int rr = m0 + r; rr = rr < 392 ? rr : 391;
            int bb = rr / 49, pp = rr % 49;
            int ph = pp / 7, pw = pp % 7;
            aoff[i] = ((long)bb * Npix + (long)(ph * Wimg + pw) * s) * 256 + ((cp ^ (r & 7)) << 3);
            boff[i] = (long)(n0 + r) * Kc + ((cp ^ (r & 7)) << 3);
        }
        int kbase = zz * 1024;
        for (int ko = 0; ko < 1024; ko += 64) {
            int k0 = kbase + ko;
            int khw = k0 >> 8;
            int kh = khw >> lgs, kw = khw & (s - 1);
            long adelta = (long)(kh * Wimg + kw) * 256 + (k0 & 255);
            __syncthreads();
            #pragma unroll
            for (int i = 0; i < 4; ++i)
                GLDS16(Xb + aoff[i] + adelta, &lsA[(w * 4 + i) * 512]);
            #pragma unroll
            for (int i = 0; i < 4; ++i)
                GLDS16(Wcp + boff[i] + k0, &lsB[(w * 4 + i) * 512]);
            __syncthreads();
            #pragma unroll
            for (int kk = 0; kk < 2; ++kk) {
                s8v af[4], bf[4];
                #pragma unroll
                for (int mf = 0; mf < 4; ++mf) {
                    int row = wr * 64 + mf * 16 + lq;
                    int ph2 = (kk * 4 + g) ^ (row & 7);
                    af[mf] = *(const s8v*)&lsA[row * 64 + ph2 * 8];
                }
                #pragma unroll
                for (int nf = 0; nf < 4; ++nf) {
                    int row = wc * 64 + nf * 16 + lq;
                    int ph2 = (kk * 4 + g) ^ (row & 7);
                    bf[nf] = *(const s8v*)&lsB[row * 64 + ph2 * 8];
                }
                #pragma unroll
                for (int mf = 0; mf < 4; ++mf)
                    #pragma unroll
                    for (int nf = 0; nf < 4; ++nf)
                        acc[mf][nf] = __builtin_amdgcn_mfma_f32_16x16x32_bf16(
                            af[mf], bf[nf], acc[mf][nf], 0, 0, 0);
            }
        }
        float* Cb = Co + (size_t)zz * 392 * 256;
        #pragma unroll
        for (int mf = 0; mf < 4; ++mf)
            #pragma unroll
            for (int r = 0; r < 4; ++r) {
                int grow = m0 + wr * 64 + mf * 16 + g * 4 + r;
                if (grow < 392) {
                    #pragma unroll
                    for (int nf = 0; nf < 4; ++nf) {
                        int col = n0 + wc * 64 + nf * 16 + lq;
                        Cb[(size_t)grow * 256 + col] = acc[mf][nf][r];
                    }
                }
            }
    }
}

// ---------------------------------------------------------------------------
// LayerNorm: sum conv slices (16 / 4) + conv bias, normalize, write bf16.
// ---------------------------------------------------------------------------
__global__ __launch_bounds__(256) void ln_kernel(
    const float* __restrict__ xr0, const float* __restrict__ xr1,
    const float* __restrict__ srb0, const float* __restrict__ srb1,
    const float* __restrict__ n0w, const float* __restrict__ n0b,
    const float* __restrict__ n1w, const float* __restrict__ n1b,
    u16* __restrict__ lnb)
{
    int row = blockIdx.x;            // 0..783
    int b = row / 98, j = row % 98;
    int c = threadIdx.x;
    const float* src; int sidx, ns;
    const float *bs, *nw, *nb;
    if (j < 49) { src = xr0; sidx = b * 49 + j;       ns = 16; bs = srb0; nw = n0w; nb = n0b; }
    else        { src = xr1; sidx = b * 49 + (j - 49); ns = 4; bs = srb1; nw = n1w; nb = n1b; }
    float v = bs[c];
    for (int sl = 0; sl < ns; ++sl) v += src[(size_t)sl * 100352 + (size_t)sidx * 256 + c];
    __shared__ float red[8];
    float sumv = v;
    #pragma unroll
    for (int off = 32; off; off >>= 1) sumv += __shfl_down(sumv, off, 64);
    int wid = c >> 6, lane = c & 63;
    if (lane == 0) red[wid] = sumv;
    __syncthreads();
    float mu = (red[0] + red[1] + red[2] + red[3]) * (1.0f / 256.0f);
    float dv = v - mu;
    float s2 = dv * dv;
    #pragma unroll
    for (int off = 32; off; off >>= 1) s2 += __shfl_down(s2, off, 64);
    if (lane == 0) red[4 + wid] = s2;
    __syncthreads();
    float var = (red[4] + red[5] + red[6] + red[7]) * (1.0f / 256.0f);
    float rr = rsqrtf(var + 1e-5f);
    lnb[(size_t)row * 256 + c] = f2bf(dv * rr * nw[c] + nb[c]);
}

// ---------------------------------------------------------------------------
// KV projection -> Kb[bh][112][32] (rows>=98 zero), Vtb[bh][32][128]
// (cols>=98 zero). Grid (4, 1, 8).
// ---------------------------------------------------------------------------
__global__ __launch_bounds__(256) void kv_kernel(
    const u16* __restrict__ A, const u16* __restrict__ Bw,
    u16* __restrict__ Kb, u16* __restrict__ Vtb)
{
    __shared__ u16 lsA[128 * 64];
    __shared__ u16 lsB[128 * 64];
    int tid = threadIdx.x;
    int w = tid >> 6, l = tid & 63, g = l >> 4, lq = l & 15;
    int wr = w >> 1, wc = w & 1;
    int n0 = blockIdx.x * 128;
    int bz = blockIdx.z;
    const u16* Ab = A + (size_t)bz * 98 * 256;

    long aoff[4], boff[4];
    #pragma unroll
    for (int i = 0; i < 4; ++i) {
        int p = (w * 4 + i) * 64 + l;
        int r = p >> 3, cp = p & 7;
        int ar = r < 98 ? r : 97;
        aoff[i] = (long)ar * 256 + ((cp ^ (r & 7)) << 3);
        boff[i] = (long)(n0 + r) * 256 + ((cp ^ (r & 7)) << 3);
    }
    f4 acc[4][4];
    #pragma unroll
    for (int i = 0; i < 4; ++i)
        #pragma unroll
        for (int j = 0; j < 4; ++j) acc[i][j] = (f4){0.f, 0.f, 0.f, 0.f};

    for (int k0 = 0; k0 < 256; k0 += 64) {
        __syncthreads();
        #pragma unroll
        for (int i = 0; i < 4; ++i)
            GLDS16(Ab + aoff[i] + k0, &lsA[(w * 4 + i) * 512]);
        #pragma unroll
        for (int i = 0; i < 4; ++i)
            GLDS16(Bw + boff[i] + k0, &lsB[(w * 4 + i) * 512]);
        __syncthreads();
        #pragma unroll
        for (int kk = 0; kk < 2; ++kk) {
            s8v af[4], bf[4];
            #pragma unroll
            for (int mf = 0; mf < 4; ++mf) {
                int row = wr * 64 + mf * 16 + lq;
                int ph = (kk * 4 + g) ^ (row & 7);
                af[mf] = *(const s8v*)&lsA[row * 64 + ph * 8];
            }
            #pragma unroll
            for (int nf = 0; nf < 4; ++nf) {
                int row = wc * 64 + nf * 16 + lq;
                int ph = (kk * 4 + g) ^ (row & 7);
                bf[nf] = *(const s8v*)&lsB[row * 64 + ph * 8];
            }
            #pragma unroll
            for (int mf = 0; mf < 4; ++mf)
                #pragma unroll
                for (int nf = 0; nf < 4; ++nf)
                    acc[mf][nf] = __builtin_amdgcn_mfma_f32_16x16x32_bf16(
                        af[mf], bf[nf], acc[mf][nf], 0, 0, 0);
        }
    }
    #pragma unroll
    for (int mf = 0; mf < 4; ++mf)
        #pragma unroll
        for (int r = 0; r < 4; ++r) {
            int grow = wr * 64 + mf * 16 + g * 4 + r;   // 0..127
            #pragma unroll
            for (int nf = 0; nf < 4; ++nf) {
                int col = n0 + wc * 64 + nf * 16 + lq;
                u16 bv = (grow < 98) ? f2bf(acc[mf][nf][r]) : (u16)0;
                if (col < 256) {
                    if (grow < 112)
                        Kb[((size_t)(bz * 8 + (col >> 5)) * 112 + grow) * 32 + (col & 31)] = bv;
                } else {
                    int cc = col - 256;
                    Vtb[((size_t)(bz * 8 + (cc >> 5)) * 32 + (cc & 31)) * 128 + grow] = bv;
                }
            }
        }
}

// ---------------------------------------------------------------------------
// Fused attention + output projection. Grid (62, 8), 512 threads (8 waves).
// K-fragments hoisted out of the qt loop (qt-invariant; compiler wasn't
// hoisting — VGPR 56 -> ~84, still 6 waves/SIMD = LDS cap). setprio(1)
// around MFMA clusters (T5: helps attn's phase-diverse waves).
// ---------------------------------------------------------------------------
#define SCALE_F 0.1767766952966369f
__global__ __launch_bounds__(512) void attnout_kernel(
    const u16* __restrict__ Yq, const u16* __restrict__ Kb,
    const u16* __restrict__ Vtb, const u16* __restrict__ pwb,
    const float* __restrict__ proj_b, float* __restrict__ out)
{
    __shared__ u16 Ps[8][16 * 128];    // per-wave P scratch (4 KB each)
    __shared__ u16 Os[64 * 256];       // O panel, swizzled (32 KB)
    int tid = threadIdx.x;
    int w = tid >> 6, l = tid & 63, g = l >> 4, lq = l & 15;
    int b = blockIdx.y, h = w;
    int n0 = blockIdx.x * 64;
    const u16* Kh = Kb + (size_t)(b * 8 + h) * 112 * 32;
    const u16* Vh = Vtb + (size_t)(b * 8 + h) * 32 * 128;
    u16* Pw = Ps[w];

    // zero P pad granules 14,15 (keys 112..127) once
    if (l < 32) {
        int row = l >> 1;
        int gr = (14 + (l & 1)) ^ (row & 7);
        *(s8v*)&Pw[row * 128 + gr * 8] = (s8v){0, 0, 0, 0, 0, 0, 0, 0};
    }

    // hoist K fragments (qt-invariant): 7 x s8v = 28 VGPRs
    s8v kf[7];
    #pragma unroll
    for (int f = 0; f < 7; ++f)
        kf[f] = *(const s8v*)(Kh + (f * 16 + lq) * 32 + g * 8);

    for (int qt = 0; qt < 4; ++qt) {
        int qrow = n0 + qt * 16 + lq;
        int qr = qrow < 3920 ? qrow : 3919;
        s8v qf = *(const s8v*)(Yq + ((size_t)b * 3920 + qr) * 256 + h * 32 + g * 8);
        f4 sacc[7];
        __builtin_amdgcn_s_setprio(1);
        #pragma unroll
        for (int f = 0; f < 7; ++f) {
            f4 zz = (f4){0.f, 0.f, 0.f, 0.f};
            sacc[f] = __builtin_amdgcn_mfma_f32_16x16x32_bf16(kf[f], qf, zz, 0, 0, 0);
        }
        __builtin_amdgcn_s_setprio(0);
        float pm = -1e30f;
        float sv[7][4];
        #pragma unroll
        for (int f = 0; f < 7; ++f)
            #pragma unroll
            for (int r = 0; r < 4; ++r) {
                int key = f * 16 + g * 4 + r;
                float v = sacc[f][r] * SCALE_F;
                if (key >= 98) v = -1e30f;
                sv[f][r] = v;
                pm = fmaxf(pm, v);
            }
        pm = fmaxf(pm, __shfl_xor(pm, 16));
        pm = fmaxf(pm, __shfl_xor(pm, 32));
        float sum = 0.f;
        float pv[7][4];
        #pragma unroll
        for (int f = 0; f < 7; ++f)
            #pragma unroll
            for (int r = 0; r < 4; ++r) {
                float e = __expf(sv[f][r] - pm);
                pv[f][r] = e;
                sum += e;
            }
        sum += __shfl_xor(sum, 16);
        sum += __shfl_xor(sum, 32);
        float inv = 1.0f / sum;

        #pragma unroll
        for (int f = 0; f < 7; ++f)
            #pragma unroll
            for (int pr = 0; pr < 2; ++pr) {
                u32 pk = (u32)f2bf(pv[f][2 * pr] * inv) |
                         ((u32)f2bf(pv[f][2 * pr + 1] * inv) << 16);
                int k = f * 16 + g * 4 + pr * 2;
                int gr = (k >> 3) ^ (lq & 7);
                *(u32*)&Pw[lq * 128 + gr * 8 + (k & 7)] = pk;
            }

        f4 o0 = (f4){0.f, 0.f, 0.f, 0.f}, o1 = (f4){0.f, 0.f, 0.f, 0.f};
        __builtin_amdgcn_s_setprio(1);
        #pragma unroll
        for (int s4 = 0; s4 < 4; ++s4) {
            int gv = s4 * 4 + g;
            s8v pa = *(const s8v*)&Pw[lq * 128 + ((gv ^ (lq & 7)) * 8)];
            s8v vf0 = *(const s8v*)(Vh + (size_t)lq * 128 + s4 * 32 + g * 8);
            s8v vf1 = *(const s8v*)(Vh + (size_t)(16 + lq) * 128 + s4 * 32 + g * 8);
            o0 = __builtin_amdgcn_mfma_f32_16x16x32_bf16(pa, vf0, o0, 0, 0, 0);
            o1 = __builtin_amdgcn_mfma_f32_16x16x32_bf16(pa, vf1, o1, 0, 0, 0);
        }
        __builtin_amdgcn_s_setprio(0);
        #pragma unroll
        for (int r = 0; r < 4; ++r) {
            int R = qt * 16 + g * 4 + r;
            #pragma unroll
            for (int half = 0; half < 2; ++half) {
                int C = h * 32 + half * 16 + lq;
                int sg = (C >> 3) ^ (R & 7);
                Os[R * 256 + sg * 8 + (C & 7)] = f2bf(half ? o1[r] : o0[r]);
            }
        }
    }
    __syncthreads();

    // ---- out-proj: C[64 x 256] = O[64 x 256] * pwb^T + bias ----
    f4 acc[4][2];
    #pragma unroll
    for (int i = 0; i < 4; ++i) {
        acc[i][0] = (f4){0.f, 0.f, 0.f, 0.f};
        acc[i][1] = (f4){0.f, 0.f, 0.f, 0.f};
    }
    for (int k0 = 0; k0 < 256; k0 += 32) {
        s8v af[4], bf[2];
        int kgr = (k0 >> 3) + g;
        #pragma unroll
        for (int mf = 0; mf < 4; ++mf) {
            int row = mf * 16 + lq;
            af[mf] = *(const s8v*)&Os[row * 256 + ((kgr ^ (row & 7)) * 8)];
        }
        #pragma unroll
        for (int nf = 0; nf < 2; ++nf) {
            int n = w * 32 + nf * 16 + lq;
            bf[nf] = *(const s8v*)(pwb + (size_t)n * 256 + k0 + g * 8);
        }
        __builtin_amdgcn_s_setprio(1);
        #pragma unroll
        for (int mf = 0; mf < 4; ++mf)
            #pragma unroll
            for (int nf = 0; nf < 2; ++nf)
                acc[mf][nf] = __builtin_amdgcn_mfma_f32_16x16x32_bf16(
                    af[mf], bf[nf], acc[mf][nf], 0, 0, 0);
        __builtin_amdgcn_s_setprio(0);
    }
    #pragma unroll
    for (int mf = 0; mf < 4; ++mf)
        #pragma unroll
        for (int r = 0; r < 4; ++r) {
            int grow = n0 + mf * 16 + g * 4 + r;
            if (grow < 3920) {
                #pragma unroll
                for (int nf = 0; nf < 2; ++nf) {
                    int col = w * 32 + nf * 16 + lq;
                    out[((size_t)b * 3920 + grow) * 256 + col] = acc[mf][nf][r] + proj_b[col];
                }
            }
        }
}

// ---------------------------------------------------------------------------
extern "C" void kernel_launch(void* const* d_in, const int* in_sizes, int n_in,
                              void* d_out, int out_size, void* d_ws, size_t ws_size,
                              hipStream_t stream)
{
    const float* x0     = (const float*)d_in[0];
    const float* x1     = (const float*)d_in[1];
    const float* q_w    = (const float*)d_in[2];
    const float* kv_w   = (const float*)d_in[3];
    const float* proj_w = (const float*)d_in[4];
    const float* proj_b = (const float*)d_in[5];
    const float* sr0_w  = (const float*)d_in[6];
    const float* sr0_b  = (const float*)d_in[7];
    const float* sr1_w  = (const float*)d_in[8];
    const float* sr1_b  = (const float*)d_in[9];
    const float* n0w    = (const float*)d_in[10];
    const float* n0b    = (const float*)d_in[11];
    const float* n1w    = (const float*)d_in[12];
    const float* n1b    = (const float*)d_in[13];
    (void)in_sizes; (void)n_in; (void)out_size; (void)ws_size;

    float* ws = (float*)d_ws;
    u16*  Yq   = (u16*)ws;                         // [8][3920][256] bf16
    u16*  x0b  = (u16*)(ws + 4014080);             // [25088][256] bf16
    u16*  x1b  = (u16*)(ws + 7225344);             // [6272][256] bf16
    float* xr0 = ws + 8028160;                     // [16][392][256] fp32 slices
    float* xr1 = ws + 9633792;                     // [4][392][256]
    u16*  Kb   = (u16*)(ws + 10035200);            // [64][112][32] bf16
    u16*  Vtb  = (u16*)(ws + 10149888);            // [64][32][128] bf16
    u16*  qwb  = (u16*)(ws + 10280960);            // [256][256] bf16
    u16*  kvwb = (u16*)(ws + 10313728);            // [512][256] bf16
    u16*  pwb  = (u16*)(ws + 10379264);            // [256][256] bf16
    u16*  Wc0  = (u16*)(ws + 10412032);            // [256][16384] bf16
    u16*  Wc1  = (u16*)(ws + 12509184);            // [256][4096] bf16
    u16*  lnb  = (u16*)(ws + 13033472);            // [784][256] bf16

    // 1. fused prep: LDS-transposed conv weights + flat converts
    prep_kernel<<<2048, 256, 0, stream>>>(
        x0, x1, q_w, kv_w, proj_w, sr0_w, sr1_w,
        x0b, x1b, qwb, kvwb, pwb, Wc0, Wc1);

    // 2. convs (long, first) + Q projection (short, backfill), one dispatch
    qc_kernel<<<656, 256, 0, stream>>>(x0b, x1b, qwb, Yq, Wc0, Wc1, xr0, xr1);

    // 3. layernorm (+conv bias, slice reduce) -> bf16, 784 blocks
    ln_kernel<<<784, 256, 0, stream>>>(xr0, xr1, sr0_b, sr1_b, n0w, n0b, n1w, n1b, lnb);

    // 4. KV projection -> Kb/Vtb (attnout layouts)
    kv_kernel<<<dim3(4, 1, 8), 256, 0, stream>>>(lnb, kvwb, Kb, Vtb);

    // 5. fused attention + output projection -> d_out fp32
    attnout_kernel<<<dim3(62, 8), 512, 0, stream>>>(
        Yq, Kb, Vtb, pwb, proj_b, (float*)d_out);
}